// Round 12
// baseline (5322.027 us; speedup 1.0000x reference)
//
#include <hip/hip_runtime.h>

#define HDIM 64
#define NFEAT 32
#define NEMB 32
#define GBATCH 128
#define MAXD 48
#define SPILL_CAP 4096
#define POOLSPLIT 8

// partition path
#define NBUCK 1024
#define BSHIFT 7                 // 128 nodes per bucket
#define BNODES (1 << BSHIFT)
#define BCAP 2048
#define CHUNK 6144
#define PBLOCK 1024
#define EPT (CHUNK / PBLOCK)     // 6 edges per thread
#define SRCBITS 20
#define SRCMASK ((1 << SRCBITS) - 1)

// ================= tier 1: partition + bucket-local CSR =================

__global__ void zero_part_kernel(int* __restrict__ bucketCnt, int* __restrict__ spillCnt) {
    int i = blockIdx.x * blockDim.x + threadIdx.x;
    if (i < NBUCK) bucketCnt[i] = 0;
    if (i == 0) *spillCnt = 0;
}

// LDS-staged partition: edges -> 1024 dst-buckets, contiguous writes (round-10, proven)
__global__ __launch_bounds__(PBLOCK) void partition_kernel(
    const int* __restrict__ ei, const float* __restrict__ ew,
    int* __restrict__ bucketCnt, int2* __restrict__ bucket,
    int4* __restrict__ spill, int* __restrict__ spillCnt, int E)
{
    __shared__ int2 stage[CHUNK];   // 48 KB
    __shared__ int hist[NBUCK];     // 4 KB
    __shared__ int cursor[NBUCK];   // 4 KB
    __shared__ int gbase[NBUCK];    // 4 KB
    __shared__ int tsum[PBLOCK];    // 4 KB   (64 KB total)

    int t = threadIdx.x;
    int c0 = blockIdx.x * CHUNK;
    if (c0 >= E) return;
    int nE = min(CHUNK, E - c0);

    hist[t] = 0;                    // NBUCK == PBLOCK
    __syncthreads();

    int2 re[EPT];
    int  rb[EPT];
    #pragma unroll
    for (int j = 0; j < EPT; ++j) {
        int i = t + j * PBLOCK;
        if (i < nE) {
            int src = ei[c0 + i];
            int d   = ei[E + c0 + i];
            float w = ew[c0 + i];
            int b = d >> BSHIFT;
            re[j] = make_int2(src | ((d & (BNODES - 1)) << SRCBITS), __float_as_int(w));
            rb[j] = b;
            atomicAdd(&hist[b], 1);
        } else {
            rb[j] = -1;
        }
    }
    __syncthreads();

    int s = hist[t];
    tsum[t] = s;
    __syncthreads();
    for (int d = 1; d < PBLOCK; d <<= 1) {
        int v = (t >= d) ? tsum[t - d] : 0;
        __syncthreads();
        tsum[t] += v;
        __syncthreads();
    }
    cursor[t] = tsum[t] - s;
    gbase[t]  = (s > 0) ? atomicAdd(&bucketCnt[t], s) : 0;
    __syncthreads();

    #pragma unroll
    for (int j = 0; j < EPT; ++j) {
        if (rb[j] >= 0) {
            int pos = atomicAdd(&cursor[rb[j]], 1);
            stage[pos] = re[j];
        }
    }
    __syncthreads();

    int wid = t >> 6, lane = t & 63;
    for (int b = wid; b < NBUCK; b += (PBLOCK / 64)) {
        int h = hist[b];
        if (h == 0) continue;
        int lbase = cursor[b] - h;
        int gb = gbase[b];
        for (int k = lane; k < h; k += 64) {
            int2 ed = stage[lbase + k];
            int gpos = gb + k;
            if (gpos < BCAP) {
                bucket[(size_t)b * BCAP + gpos] = ed;
            } else {
                int sp = atomicAdd(spillCnt, 1);
                if (sp < SPILL_CAP)
                    spill[sp] = make_int4(ed.x & SRCMASK,
                                          (b << BSHIFT) + (ed.x >> SRCBITS), ed.y, 0);
            }
        }
    }
}

// in-LDS sort of each bucket into per-node contiguous runs; emits off/ncnt/deg
__global__ __launch_bounds__(256) void localsort_kernel(
    int2* __restrict__ bucket, const int* __restrict__ bucketCnt,
    int* __restrict__ off, int* __restrict__ ncnt, float* __restrict__ deg, int N)
{
    __shared__ int2 seg[BCAP];      // 16 KB
    __shared__ int2 sorted[BCAP];   // 16 KB
    __shared__ int h128[BNODES];
    __shared__ int sc[BNODES];
    __shared__ int cur[BNODES];

    int b = blockIdx.x;
    int t = threadIdx.x;
    int cnt = min(bucketCnt[b], BCAP);
    int2* gseg = bucket + (size_t)b * BCAP;

    for (int i = t; i < cnt; i += 256) seg[i] = gseg[i];
    if (t < BNODES) h128[t] = 0;
    __syncthreads();
    for (int i = t; i < cnt; i += 256)
        atomicAdd(&h128[seg[i].x >> SRCBITS], 1);
    __syncthreads();

    if (t < BNODES) sc[t] = h128[t];
    __syncthreads();
    for (int d = 1; d < BNODES; d <<= 1) {
        int v = 0;
        if (t < BNODES && t >= d) v = sc[t - d];
        __syncthreads();
        if (t < BNODES) sc[t] += v;
        __syncthreads();
    }
    if (t < BNODES) cur[t] = sc[t] - h128[t];
    __syncthreads();

    for (int i = t; i < cnt; i += 256) {
        int dlow = seg[i].x >> SRCBITS;
        int p = atomicAdd(&cur[dlow], 1);
        sorted[p] = seg[i];
    }
    __syncthreads();

    for (int i = t; i < cnt; i += 256) gseg[i] = sorted[i];

    if (t < BNODES) {
        int n = (b << BSHIFT) + t;
        if (n < N) {
            int st = sc[t] - h128[t];
            int c  = h128[t];
            float s = 1.0f;                      // self-loop weight
            for (int j = 0; j < c; ++j) s += __int_as_float(sorted[st + j].y);
            off[n]  = b * BCAP + st;
            ncnt[n] = c;
            deg[n]  = s;
        }
    }
}

__global__ void spill_deg_kernel(const int4* __restrict__ spill, const int* __restrict__ spillCnt,
                                 float* __restrict__ deg) {
    int e = blockIdx.x * blockDim.x + threadIdx.x;
    int ns = min(*spillCnt, SPILL_CAP);
    if (e < ns) atomicAdd(&deg[spill[e].y], __int_as_float(spill[e].z));
}

__global__ void dinv_kernel(float* __restrict__ deg, int N) {
    int i = blockIdx.x * blockDim.x + threadIdx.x;
    if (i < N) {
        float d = deg[i];
        deg[i] = (d > 0.f) ? rsqrtf(d) : 0.f;
    }
}

// precompute norm_e = dinv[src]*w*dinv[dst] in place (.y); shared by both layers
__global__ __launch_bounds__(256) void norm_kernel(
    int2* __restrict__ bucket, const int* __restrict__ bucketCnt,
    const float* __restrict__ dinv)
{
    int b = blockIdx.x;
    int cnt = min(bucketCnt[b], BCAP);
    int2* seg = bucket + (size_t)b * BCAP;
    for (int i = threadIdx.x; i < cnt; i += 256) {
        int2 ed = seg[i];
        int src  = ed.x & SRCMASK;
        int dst  = (b << BSHIFT) + (ed.x >> SRCBITS);
        float nm = dinv[src] * __int_as_float(ed.y) * dinv[dst];
        seg[i] = make_int2(ed.x, __float_as_int(nm));
    }
}

// ---- fused: layer-0 aggregation (into LDS, raw) + layer-1 GEMM (relu on read) ----
// block = 64 nodes; phase A: wave-per-node float2 agg; phase B: tile GEMM with W1.
__global__ __launch_bounds__(256) void fused_agg_gemm_kernel(
    const int* __restrict__ off, const int* __restrict__ ncnt, const int2* __restrict__ bucket,
    const float* __restrict__ hw, const float* __restrict__ dinv,
    const float* __restrict__ b0, const float* __restrict__ W1,
    const int4* __restrict__ spill, const int* __restrict__ spillCnt,
    float* __restrict__ hout, int N)
{
    __shared__ float ins[64][HDIM];   // 16 KB: raw (pre-relu) layer-0 outputs
    int t = threadIdx.x;
    int nodeBase = blockIdx.x * 64;
    int wid = t >> 6, lane = t & 63;
    int half = lane >> 5, l = lane & 31;
    const float2* hw2 = (const float2*)hw;

    // phase A: wave wid aggregates nodes nodeBase + wid + 4*i
    for (int i = 0; i < 16; ++i) {
        int nrow = wid + 4 * i;
        int n = nodeBase + nrow;
        float ox = 0.f, oy = 0.f;
        if (n < N) {
            int c = ncnt[n];
            const int2* row = bucket + off[n];
            float2 a0 = {0.f,0.f}, a1 = {0.f,0.f}, a2 = {0.f,0.f}, a3 = {0.f,0.f};
            int j = 0;
            for (; j + 7 < c; j += 8) {
                int2 e0 = row[j     + half];
                int2 e1 = row[j + 2 + half];
                int2 e2 = row[j + 4 + half];
                int2 e3 = row[j + 6 + half];
                float2 v0 = hw2[(size_t)(e0.x & SRCMASK) * 32 + l];
                float2 v1 = hw2[(size_t)(e1.x & SRCMASK) * 32 + l];
                float2 v2 = hw2[(size_t)(e2.x & SRCMASK) * 32 + l];
                float2 v3 = hw2[(size_t)(e3.x & SRCMASK) * 32 + l];
                float n0 = __int_as_float(e0.y), n1 = __int_as_float(e1.y);
                float n2 = __int_as_float(e2.y), n3 = __int_as_float(e3.y);
                a0.x += n0 * v0.x; a0.y += n0 * v0.y;
                a1.x += n1 * v1.x; a1.y += n1 * v1.y;
                a2.x += n2 * v2.x; a2.y += n2 * v2.y;
                a3.x += n3 * v3.x; a3.y += n3 * v3.y;
            }
            for (; j < c; j += 2) {
                int jj = j + half;
                if (jj < c) {
                    int2 e0 = row[jj];
                    float2 v0 = hw2[(size_t)(e0.x & SRCMASK) * 32 + l];
                    float n0 = __int_as_float(e0.y);
                    a0.x += n0 * v0.x; a0.y += n0 * v0.y;
                }
            }
            float Ax = (a0.x + a1.x) + (a2.x + a3.x);
            float Ay = (a0.y + a1.y) + (a2.y + a3.y);
            Ax += __shfl_xor(Ax, 32, 64);
            Ay += __shfl_xor(Ay, 32, 64);
            float dn = dinv[n];
            float2 self = hw2[(size_t)n * 32 + l];
            float2 bb = ((const float2*)b0)[l];
            ox = Ax + dn * dn * self.x + bb.x;
            oy = Ay + dn * dn * self.y + bb.y;
        }
        if (half == 0) {
            float2 o = {ox, oy};
            ((float2*)ins[nrow])[l] = o;
        }
    }
    __syncthreads();

    // rare spill edges targeting this tile (pre-relu adds)
    int nsp = min(*spillCnt, SPILL_CAP);
    if (nsp > 0) {
        for (int i = t; i < nsp; i += 256) {
            int4 sp = spill[i];
            int dl = sp.y - nodeBase;
            if (dl >= 0 && dl < 64) {
                float nm = dinv[sp.x] * __int_as_float(sp.z) * dinv[sp.y];
                for (int k = 0; k < HDIM; ++k)
                    atomicAdd(&ins[dl][k], nm * hw[(size_t)sp.x * HDIM + k]);
            }
        }
    }

    float wcol[HDIM];
    #pragma unroll
    for (int kk = 0; kk < HDIM; ++kk) wcol[kk] = W1[kk * HDIM + lane];
    __syncthreads();

    // phase B: GEMM with relu applied on read
    for (int it = 0; it < 16; ++it) {
        int nrow = it * 4 + wid;
        int n = nodeBase + nrow;
        float acc = 0.f;
        #pragma unroll
        for (int kk = 0; kk < HDIM; ++kk)
            acc += fmaxf(ins[nrow][kk], 0.f) * wcol[kk];
        if (n < N) hout[(size_t)n * HDIM + lane] = acc;
    }
}

// ---- fused: layer-1 aggregation + bias + relu + mean-pool atomic ----
__global__ __launch_bounds__(256) void fused_agg_pool_kernel(
    const int* __restrict__ off, const int* __restrict__ ncnt, const int2* __restrict__ bucket,
    const float* __restrict__ hw, const float* __restrict__ dinv,
    const float* __restrict__ b1, const int* __restrict__ batch,
    const int4* __restrict__ spill, const int* __restrict__ spillCnt,
    float* __restrict__ out, int N)
{
    int gid = blockIdx.x * blockDim.x + threadIdx.x;
    int n = gid >> 6, lane = gid & 63;
    if (n >= N) return;
    int half = lane >> 5, l = lane & 31;
    int c = ncnt[n];
    const int2* row = bucket + off[n];
    const float2* hw2 = (const float2*)hw;

    float2 a0 = {0.f,0.f}, a1 = {0.f,0.f}, a2 = {0.f,0.f}, a3 = {0.f,0.f};
    int j = 0;
    for (; j + 7 < c; j += 8) {
        int2 e0 = row[j     + half];
        int2 e1 = row[j + 2 + half];
        int2 e2 = row[j + 4 + half];
        int2 e3 = row[j + 6 + half];
        float2 v0 = hw2[(size_t)(e0.x & SRCMASK) * 32 + l];
        float2 v1 = hw2[(size_t)(e1.x & SRCMASK) * 32 + l];
        float2 v2 = hw2[(size_t)(e2.x & SRCMASK) * 32 + l];
        float2 v3 = hw2[(size_t)(e3.x & SRCMASK) * 32 + l];
        float n0 = __int_as_float(e0.y), n1 = __int_as_float(e1.y);
        float n2 = __int_as_float(e2.y), n3 = __int_as_float(e3.y);
        a0.x += n0 * v0.x; a0.y += n0 * v0.y;
        a1.x += n1 * v1.x; a1.y += n1 * v1.y;
        a2.x += n2 * v2.x; a2.y += n2 * v2.y;
        a3.x += n3 * v3.x; a3.y += n3 * v3.y;
    }
    for (; j < c; j += 2) {
        int jj = j + half;
        if (jj < c) {
            int2 e0 = row[jj];
            float2 v0 = hw2[(size_t)(e0.x & SRCMASK) * 32 + l];
            float n0 = __int_as_float(e0.y);
            a0.x += n0 * v0.x; a0.y += n0 * v0.y;
        }
    }
    float Ax = (a0.x + a1.x) + (a2.x + a3.x);
    float Ay = (a0.y + a1.y) + (a2.y + a3.y);
    Ax += __shfl_xor(Ax, 32, 64);
    Ay += __shfl_xor(Ay, 32, 64);

    if (half == 0) {
        float dn = dinv[n];
        float2 self = hw2[(size_t)n * 32 + l];
        float2 bb = ((const float2*)b1)[l];
        float ox = Ax + dn * dn * self.x + bb.x;
        float oy = Ay + dn * dn * self.y + bb.y;
        int nsp = min(*spillCnt, SPILL_CAP);
        if (nsp > 0) {
            for (int i = 0; i < nsp; ++i) {
                int4 sp = spill[i];
                if (sp.y == n) {
                    float nm = dinv[sp.x] * __int_as_float(sp.z) * dinv[sp.y];
                    float2 v = hw2[(size_t)sp.x * 32 + l];
                    ox += nm * v.x; oy += nm * v.y;
                }
            }
        }
        int g = batch[n];
        atomicAdd(&out[g * HDIM + 2 * l],     fmaxf(ox, 0.f));
        atomicAdd(&out[g * HDIM + 2 * l + 1], fmaxf(oy, 0.f));
    }
}

__global__ __launch_bounds__(256) void spill_agg_kernel(
    const int4* __restrict__ spill, const int* __restrict__ spillCnt,
    const float* __restrict__ hw, const float* __restrict__ dinv, float* __restrict__ hout)
{
    int gid = blockIdx.x * blockDim.x + threadIdx.x;
    int e = gid >> 6, lane = gid & 63;
    int ns = min(*spillCnt, SPILL_CAP);
    if (e >= ns) return;
    int4 sp = spill[e];
    float nm = dinv[sp.x] * __int_as_float(sp.z) * dinv[sp.y];
    atomicAdd(&hout[(size_t)sp.y * HDIM + lane], nm * hw[(size_t)sp.x * HDIM + lane]);
}

// ================= shared: GEMM =================

template<int LAYER>
__global__ __launch_bounds__(256) void gemm_kernel(
    const float* __restrict__ x, const int* __restrict__ mapping,
    const float* __restrict__ emb, const float* __restrict__ hin,
    const float* __restrict__ W, float* __restrict__ hw, int N)
{
    __shared__ float ins[64][HDIM];   // 16 KB
    int t = threadIdx.x;
    int nodeBase = blockIdx.x * 64;

    for (int i = t; i < 64 * HDIM; i += 256) {
        int nr = i >> 6, k = i & 63;
        int n = nodeBase + nr;
        float v = 0.f;
        if (n < N) {
            if (LAYER == 0) {
                v = (k < NFEAT) ? x[(size_t)n * NFEAT + k]
                                : emb[(size_t)mapping[n] * NEMB + (k - NFEAT)];
            } else {
                v = fmaxf(hin[(size_t)n * HDIM + k], 0.f);
            }
        }
        ins[nr][k] = v;
    }

    int k = t & 63;
    float wcol[HDIM];
    #pragma unroll
    for (int kk = 0; kk < HDIM; ++kk) wcol[kk] = W[kk * HDIM + k];
    __syncthreads();

    int nl = t >> 6;
    for (int ns = 0; ns < 16; ++ns) {
        int nrow = ns * 4 + nl;
        int n = nodeBase + nrow;
        float acc = 0.f;
        #pragma unroll
        for (int kk = 0; kk < HDIM; ++kk)
            acc += ins[nrow][kk] * wcol[kk];
        if (n < N) hw[(size_t)n * HDIM + k] = acc;
    }
}

// ================= tier 2: ELL path (round-6, proven 550 us) =================

__global__ void init_ell_kernel(int* __restrict__ cnt, int* __restrict__ spillCnt, int N) {
    int i = blockIdx.x * blockDim.x + threadIdx.x;
    if (i < N) cnt[i] = 0;
    if (i == 0) *spillCnt = 0;
}

__global__ void ell_fill_kernel(const int* __restrict__ ei, const float* __restrict__ ew,
                                int* __restrict__ cnt, int2* __restrict__ ell,
                                int4* __restrict__ spill, int* __restrict__ spillCnt, int E) {
    int e = blockIdx.x * blockDim.x + threadIdx.x;
    if (e >= E) return;
    int src = ei[e];
    int dst = ei[E + e];
    float w = ew[e];
    int slot = atomicAdd(&cnt[dst], 1);
    if (slot < MAXD) {
        ell[(size_t)dst * MAXD + slot] = make_int2(src, __float_as_int(w));
    } else {
        int sp = atomicAdd(spillCnt, 1);
        if (sp < SPILL_CAP) spill[sp] = make_int4(src, dst, __float_as_int(w), 0);
    }
}

__global__ __launch_bounds__(256) void degsum_kernel(const int2* __restrict__ ell,
                                                     const int* __restrict__ cnt,
                                                     float* __restrict__ deg, int N) {
    int gid = blockIdx.x * blockDim.x + threadIdx.x;
    int n = gid >> 6, lane = gid & 63;
    if (n >= N) return;
    int c = min(cnt[n], MAXD);
    float s = (lane < c) ? __int_as_float(ell[(size_t)n * MAXD + lane].y) : 0.f;
    #pragma unroll
    for (int d = 32; d > 0; d >>= 1) s += __shfl_down(s, d, 64);
    if (lane == 0) deg[n] = 1.f + s;
}

__global__ __launch_bounds__(256) void agg_kernel(
    const int2* __restrict__ ell, const int* __restrict__ cnt,
    const float* __restrict__ hw, const float* __restrict__ dinv,
    const float* __restrict__ bias, float* __restrict__ hout, int N)
{
    int gid = blockIdx.x * blockDim.x + threadIdx.x;
    int n = gid >> 6, lane = gid & 63;
    if (n >= N) return;
    int c = min(cnt[n], MAXD);
    const int2* row = ell + (size_t)n * MAXD;
    float acc0 = 0.f, acc1 = 0.f;
    int j = 0;
    for (; j + 1 < c; j += 2) {
        int2 e0 = row[j], e1 = row[j + 1];
        acc0 += dinv[e0.x] * __int_as_float(e0.y) * hw[(size_t)e0.x * HDIM + lane];
        acc1 += dinv[e1.x] * __int_as_float(e1.y) * hw[(size_t)e1.x * HDIM + lane];
    }
    if (j < c) {
        int2 e0 = row[j];
        acc0 += dinv[e0.x] * __int_as_float(e0.y) * hw[(size_t)e0.x * HDIM + lane];
    }
    float dn = dinv[n];
    hout[(size_t)n * HDIM + lane] =
        dn * (acc0 + acc1) + dn * dn * hw[(size_t)n * HDIM + lane] + bias[lane];
}

// ================= tier 3: atomic scatter =================

__global__ void init_kernel(float* __restrict__ deg, int* __restrict__ cnt, int N) {
    int i = blockIdx.x * blockDim.x + threadIdx.x;
    if (i < N) { deg[i] = 1.0f; cnt[i] = 0; }
}

__global__ void hist_kernel(const int* __restrict__ ei, const float* __restrict__ ew,
                            float* __restrict__ deg, int* __restrict__ cnt, int E) {
    int e = blockIdx.x * blockDim.x + threadIdx.x;
    if (e < E) {
        int dst = ei[E + e];
        atomicAdd(&deg[dst], ew[e]);
        atomicAdd(&cnt[dst], 1);
    }
}

__global__ void self_init_kernel(const float* __restrict__ hw, const float* __restrict__ dinv,
                                 const float* __restrict__ b, float* __restrict__ hout, int NF) {
    int i = blockIdx.x * blockDim.x + threadIdx.x;
    if (i < NF) {
        int n = i >> 6, f = i & 63;
        float di = dinv[n];
        hout[i] = b[f] + di * di * hw[i];
    }
}

__global__ __launch_bounds__(256) void scatter_kernel(
    const int* __restrict__ ei, const float* __restrict__ ew,
    const float* __restrict__ dinv, const float* __restrict__ hw,
    float* __restrict__ hout, int E)
{
    int gid = blockIdx.x * blockDim.x + threadIdx.x;
    int e = gid >> 5, lane = gid & 31;
    if (e >= E) return;
    int src = ei[e];
    int dst = ei[E + e];
    float norm = dinv[src] * ew[e] * dinv[dst];
    float2 v = ((const float2*)hw)[(size_t)src * (HDIM / 2) + lane];
    float* o = &hout[(size_t)dst * HDIM + 2 * lane];
    atomicAdd(o,     norm * v.x);
    atomicAdd(o + 1, norm * v.y);
}

// ================= pooling (tiers 2/3) =================

__global__ void zero_out_kernel(float* __restrict__ out) {
    int i = blockIdx.x * blockDim.x + threadIdx.x;
    if (i < GBATCH * HDIM) out[i] = 0.f;
}

__global__ __launch_bounds__(256) void pool_kernel(
    const float* __restrict__ h, const int* __restrict__ batch,
    float* __restrict__ out, int N)
{
    int g = blockIdx.x / POOLSPLIT;
    int slice = blockIdx.x % POOLSPLIT;
    int t = threadIdx.x;
    int lane = t & 63, w = t >> 6;

    int lo = 0, hi = N;
    while (lo < hi) { int m = (lo + hi) >> 1; if (batch[m] < g) lo = m + 1; else hi = m; }
    int start = lo;
    hi = N;
    while (lo < hi) { int m = (lo + hi) >> 1; if (batch[m] < g + 1) lo = m + 1; else hi = m; }
    int end = lo;

    float acc = 0.f;
    for (int n = start + slice * 4 + w; n < end; n += POOLSPLIT * 4)
        acc += fmaxf(h[(size_t)n * HDIM + lane], 0.f);

    __shared__ float red[4][HDIM];
    red[w][lane] = acc;
    __syncthreads();
    if (w == 0) {
        float s = red[0][lane] + red[1][lane] + red[2][lane] + red[3][lane];
        if (s != 0.f || slice == 0) atomicAdd(&out[g * HDIM + lane], s);
    }
}

__global__ void div_kernel(float* __restrict__ out, const int* __restrict__ batch, int N) {
    int i = blockIdx.x * blockDim.x + threadIdx.x;
    if (i >= GBATCH * HDIM) return;
    int g = i >> 6;
    int lo = 0, hi = N;
    while (lo < hi) { int m = (lo + hi) >> 1; if (batch[m] < g) lo = m + 1; else hi = m; }
    int start = lo;
    hi = N;
    while (lo < hi) { int m = (lo + hi) >> 1; if (batch[m] < g + 1) lo = m + 1; else hi = m; }
    float c = (float)(lo - start);
    out[i] /= fmaxf(c, 1.f);
}

// ================= launch =================

extern "C" void kernel_launch(void* const* d_in, const int* in_sizes, int n_in,
                              void* d_out, int out_size, void* d_ws, size_t ws_size,
                              hipStream_t stream) {
    const float* x       = (const float*)d_in[0];
    const int*   mapping = (const int*)  d_in[1];
    const int*   ei      = (const int*)  d_in[2];
    const float* ew      = (const float*)d_in[3];
    const int*   batch   = (const int*)  d_in[4];
    const float* emb     = (const float*)d_in[5];
    const float* W0      = (const float*)d_in[6];
    const float* b0      = (const float*)d_in[7];
    const float* W1      = (const float*)d_in[8];
    const float* b1      = (const float*)d_in[9];
    float* out = (float*)d_out;

    const int N = in_sizes[1];
    const int E = in_sizes[2] / 2;

    const int gemmGrid = (N + 63) / 64;
    const int nodeGrid = (N * 64 + 255) / 256;
    const int spillGrid = (SPILL_CAP * 64 + 255) / 256;

    size_t need_part = (size_t)NBUCK * BCAP * 8 + (size_t)N * HDIM * 4 * 2 + (size_t)N * 4 * 3
                     + (size_t)NBUCK * 4 + (size_t)SPILL_CAP * 16 + 16;
    size_t need_ell = (size_t)N * MAXD * 8 + (size_t)N * HDIM * 4 * 2 + (size_t)N * 4 * 2
                    + (size_t)SPILL_CAP * 16 + 16;

    if (ws_size >= need_part && N <= (NBUCK << BSHIFT) && N <= (1 << SRCBITS)) {
        char* p = (char*)d_ws;
        int2*  bucket    = (int2*)p;           p += (size_t)NBUCK * BCAP * 8;
        float* bufA      = (float*)p;          p += (size_t)N * HDIM * 4;
        float* bufB      = (float*)p;          p += (size_t)N * HDIM * 4;
        float* deg       = (float*)p;          p += (size_t)N * 4;
        int*   off       = (int*)p;            p += (size_t)N * 4;
        int*   ncnt      = (int*)p;            p += (size_t)N * 4;
        int*   bucketCnt = (int*)p;            p += (size_t)NBUCK * 4;
        int4*  spill     = (int4*)p;           p += (size_t)SPILL_CAP * 16;
        int*   spillCnt  = (int*)p;

        const int nChunks = (E + CHUNK - 1) / CHUNK;

        zero_part_kernel<<<(NBUCK + 255) / 256, 256, 0, stream>>>(bucketCnt, spillCnt);
        partition_kernel<<<nChunks, PBLOCK, 0, stream>>>(ei, ew, bucketCnt, bucket, spill, spillCnt, E);
        localsort_kernel<<<NBUCK, 256, 0, stream>>>(bucket, bucketCnt, off, ncnt, deg, N);
        spill_deg_kernel<<<(SPILL_CAP + 255) / 256, 256, 0, stream>>>(spill, spillCnt, deg);
        dinv_kernel<<<(N + 255) / 256, 256, 0, stream>>>(deg, N);
        norm_kernel<<<NBUCK, 256, 0, stream>>>(bucket, bucketCnt, deg);

        // layer 0 GEMM -> bufA
        gemm_kernel<0><<<gemmGrid, 256, 0, stream>>>(x, mapping, emb, nullptr, W0, bufA, N);
        // fused: layer-0 agg + layer-1 GEMM -> bufB
        fused_agg_gemm_kernel<<<gemmGrid, 256, 0, stream>>>(
            off, ncnt, bucket, bufA, deg, b0, W1, spill, spillCnt, bufB, N);
        // fused: layer-1 agg + relu + pool
        zero_out_kernel<<<(GBATCH * HDIM + 255) / 256, 256, 0, stream>>>(out);
        fused_agg_pool_kernel<<<nodeGrid, 256, 0, stream>>>(
            off, ncnt, bucket, bufB, deg, b1, batch, spill, spillCnt, out, N);
        div_kernel<<<(GBATCH * HDIM + 255) / 256, 256, 0, stream>>>(out, batch, N);
    } else if (ws_size >= need_ell) {
        char* p = (char*)d_ws;
        int2*  ell  = (int2*)p;                p += (size_t)N * MAXD * 8;
        float* bufA = (float*)p;               p += (size_t)N * HDIM * 4;
        float* bufB = (float*)p;               p += (size_t)N * HDIM * 4;
        float* deg  = (float*)p;               p += (size_t)N * 4;
        int*   cnt  = (int*)p;                 p += (size_t)N * 4;
        int4*  spill = (int4*)p;               p += (size_t)SPILL_CAP * 16;
        int*   spillCnt = (int*)p;

        init_ell_kernel<<<(N + 255) / 256, 256, 0, stream>>>(cnt, spillCnt, N);
        ell_fill_kernel<<<(E + 255) / 256, 256, 0, stream>>>(ei, ew, cnt, ell, spill, spillCnt, E);
        degsum_kernel<<<nodeGrid, 256, 0, stream>>>(ell, cnt, deg, N);
        spill_deg_kernel<<<(SPILL_CAP + 255) / 256, 256, 0, stream>>>(spill, spillCnt, deg);
        dinv_kernel<<<(N + 255) / 256, 256, 0, stream>>>(deg, N);

        gemm_kernel<0><<<gemmGrid, 256, 0, stream>>>(x, mapping, emb, nullptr, W0, bufA, N);
        agg_kernel<<<nodeGrid, 256, 0, stream>>>(ell, cnt, bufA, deg, b0, bufB, N);
        spill_agg_kernel<<<spillGrid, 256, 0, stream>>>(spill, spillCnt, bufA, deg, bufB);

        gemm_kernel<1><<<gemmGrid, 256, 0, stream>>>(nullptr, nullptr, nullptr, bufB, W1, bufA, N);
        agg_kernel<<<nodeGrid, 256, 0, stream>>>(ell, cnt, bufA, deg, b1, bufB, N);
        spill_agg_kernel<<<spillGrid, 256, 0, stream>>>(spill, spillCnt, bufA, deg, bufB);

        zero_out_kernel<<<(GBATCH * HDIM + 255) / 256, 256, 0, stream>>>(out);
        pool_kernel<<<GBATCH * POOLSPLIT, 256, 0, stream>>>(bufB, batch, out, N);
        div_kernel<<<(GBATCH * HDIM + 255) / 256, 256, 0, stream>>>(out, batch, N);
    } else {
        char* p = (char*)d_ws;
        float* bufA = (float*)p;               p += (size_t)N * HDIM * 4;
        float* bufB = (float*)p;               p += (size_t)N * HDIM * 4;
        float* deg  = (float*)p;               p += (size_t)N * 4;
        int*   cnt  = (int*)p;

        const int NF = N * HDIM;
        const int scatGrid = (E * 32 + 255) / 256;
        init_kernel<<<(N + 255) / 256, 256, 0, stream>>>(deg, cnt, N);
        hist_kernel<<<(E + 255) / 256, 256, 0, stream>>>(ei, ew, deg, cnt, E);
        dinv_kernel<<<(N + 255) / 256, 256, 0, stream>>>(deg, N);

        gemm_kernel<0><<<gemmGrid, 256, 0, stream>>>(x, mapping, emb, nullptr, W0, bufA, N);
        self_init_kernel<<<(NF + 255) / 256, 256, 0, stream>>>(bufA, deg, b0, bufB, NF);
        scatter_kernel<<<scatGrid, 256, 0, stream>>>(ei, ew, deg, bufA, bufB, E);

        gemm_kernel<1><<<gemmGrid, 256, 0, stream>>>(nullptr, nullptr, nullptr, bufB, W1, bufA, N);
        self_init_kernel<<<(NF + 255) / 256, 256, 0, stream>>>(bufA, deg, b1, bufB, NF);
        scatter_kernel<<<scatGrid, 256, 0, stream>>>(ei, ew, deg, bufA, bufB, E);

        zero_out_kernel<<<(GBATCH * HDIM + 255) / 256, 256, 0, stream>>>(out);
        pool_kernel<<<GBATCH * POOLSPLIT, 256, 0, stream>>>(bufB, batch, out, N);
        div_kernel<<<(GBATCH * HDIM + 255) / 256, 256, 0, stream>>>(out, batch, N);
    }
}

// Round 13
// 377.677 us; speedup vs baseline: 14.0915x; 14.0915x over previous
//
#include <hip/hip_runtime.h>

#define HDIM 64
#define NFEAT 32
#define NEMB 32
#define GBATCH 128
#define MAXD 48
#define SPILL_CAP 4096
#define POOLSPLIT 8

// partition path
#define NBUCK 1024
#define BSHIFT 7                 // 128 nodes per bucket
#define BNODES (1 << BSHIFT)
#define BCAP 2048
#define CHUNK 6144
#define PBLOCK 1024
#define EPT (CHUNK / PBLOCK)     // 6 edges per thread
#define SRCBITS 20
#define SRCMASK ((1 << SRCBITS) - 1)

// ================= tier 1: partition + bucket-local CSR =================

__global__ void zero_part_kernel(int* __restrict__ bucketCnt, int* __restrict__ spillCnt) {
    int i = blockIdx.x * blockDim.x + threadIdx.x;
    if (i < NBUCK) bucketCnt[i] = 0;
    if (i == 0) *spillCnt = 0;
}

// LDS-staged partition: edges -> 1024 dst-buckets, contiguous writes.
// Scan is hierarchical (shfl wave-scan + 16 wave sums): 3 barriers vs 20.
__global__ __launch_bounds__(PBLOCK) void partition_kernel(
    const int* __restrict__ ei, const float* __restrict__ ew,
    int* __restrict__ bucketCnt, int2* __restrict__ bucket,
    int4* __restrict__ spill, int* __restrict__ spillCnt, int E)
{
    __shared__ int2 stage[CHUNK];   // 48 KB
    __shared__ int hist[NBUCK];     // 4 KB
    __shared__ int cursor[NBUCK];   // 4 KB
    __shared__ int gbase[NBUCK];    // 4 KB
    __shared__ int wsum[16];

    int t = threadIdx.x;
    int c0 = blockIdx.x * CHUNK;
    if (c0 >= E) return;
    int nE = min(CHUNK, E - c0);

    hist[t] = 0;                    // NBUCK == PBLOCK
    __syncthreads();

    int2 re[EPT];
    int  rb[EPT];
    #pragma unroll
    for (int j = 0; j < EPT; ++j) {
        int i = t + j * PBLOCK;
        if (i < nE) {
            int src = ei[c0 + i];
            int d   = ei[E + c0 + i];
            float w = ew[c0 + i];
            int b = d >> BSHIFT;
            re[j] = make_int2(src | ((d & (BNODES - 1)) << SRCBITS), __float_as_int(w));
            rb[j] = b;
            atomicAdd(&hist[b], 1);
        } else {
            rb[j] = -1;
        }
    }
    __syncthreads();

    // hierarchical exclusive scan of hist
    int s = hist[t];
    int v = s;
    #pragma unroll
    for (int d = 1; d < 64; d <<= 1) {
        int u = __shfl_up(v, d, 64);
        if ((t & 63) >= d) v += u;
    }
    if ((t & 63) == 63) wsum[t >> 6] = v;
    __syncthreads();
    if (t == 0) {
        int acc = 0;
        #pragma unroll
        for (int i = 0; i < 16; ++i) { int xx = wsum[i]; wsum[i] = acc; acc += xx; }
    }
    __syncthreads();
    cursor[t] = v - s + wsum[t >> 6];   // exclusive start of bucket t's run
    gbase[t]  = (s > 0) ? atomicAdd(&bucketCnt[t], s) : 0;
    __syncthreads();

    #pragma unroll
    for (int j = 0; j < EPT; ++j) {
        if (rb[j] >= 0) {
            int pos = atomicAdd(&cursor[rb[j]], 1);
            stage[pos] = re[j];
        }
    }
    __syncthreads();

    int wid = t >> 6, lane = t & 63;
    for (int b = wid; b < NBUCK; b += (PBLOCK / 64)) {
        int h = hist[b];
        if (h == 0) continue;
        int lbase = cursor[b] - h;      // cursor is now end-of-run
        int gb = gbase[b];
        for (int k = lane; k < h; k += 64) {
            int2 ed = stage[lbase + k];
            int gpos = gb + k;
            if (gpos < BCAP) {
                bucket[(size_t)b * BCAP + gpos] = ed;
            } else {
                int sp = atomicAdd(spillCnt, 1);
                if (sp < SPILL_CAP)
                    spill[sp] = make_int4(ed.x & SRCMASK,
                                          (b << BSHIFT) + (ed.x >> SRCBITS), ed.y, 0);
            }
        }
    }
}

// in-LDS sort of each bucket into per-node contiguous runs; emits off/ncnt/deg.
// Scan over 128 counters via shfl: 2 barriers vs 14.
__global__ __launch_bounds__(256) void localsort_kernel(
    int2* __restrict__ bucket, const int* __restrict__ bucketCnt,
    int* __restrict__ off, int* __restrict__ ncnt, float* __restrict__ deg, int N)
{
    __shared__ int2 seg[BCAP];      // 16 KB
    __shared__ int2 sorted[BCAP];   // 16 KB
    __shared__ int h128[BNODES];
    __shared__ int sc[BNODES];
    __shared__ int cur[BNODES];
    __shared__ int wtot;

    int b = blockIdx.x;
    int t = threadIdx.x;
    int cnt = min(bucketCnt[b], BCAP);
    int2* gseg = bucket + (size_t)b * BCAP;

    for (int i = t; i < cnt; i += 256) seg[i] = gseg[i];
    if (t < BNODES) h128[t] = 0;
    __syncthreads();
    for (int i = t; i < cnt; i += 256)
        atomicAdd(&h128[seg[i].x >> SRCBITS], 1);
    __syncthreads();

    // inclusive scan of h128 over 128 entries: wave0 + wave1 shfl-scan, then merge
    int s0 = 0, v = 0;
    if (t < BNODES) {
        s0 = h128[t];
        v = s0;
        #pragma unroll
        for (int d = 1; d < 64; d <<= 1) {
            int u = __shfl_up(v, d, 64);
            if ((t & 63) >= d) v += u;
        }
    }
    if (t == 63) wtot = v;
    __syncthreads();
    if (t >= 64 && t < BNODES) v += wtot;
    if (t < BNODES) { sc[t] = v; cur[t] = v - s0; }
    __syncthreads();

    for (int i = t; i < cnt; i += 256) {
        int dlow = seg[i].x >> SRCBITS;
        int p = atomicAdd(&cur[dlow], 1);
        sorted[p] = seg[i];
    }
    __syncthreads();

    for (int i = t; i < cnt; i += 256) gseg[i] = sorted[i];   // coalesced write-back

    if (t < BNODES) {
        int n = (b << BSHIFT) + t;
        if (n < N) {
            int st = sc[t] - h128[t];
            int c  = h128[t];
            float s = 1.0f;                      // self-loop weight
            for (int j = 0; j < c; ++j) s += __int_as_float(sorted[st + j].y);
            off[n]  = b * BCAP + st;
            ncnt[n] = c;
            deg[n]  = s;
        }
    }
}

__global__ void spill_deg_kernel(const int4* __restrict__ spill, const int* __restrict__ spillCnt,
                                 float* __restrict__ deg) {
    int e = blockIdx.x * blockDim.x + threadIdx.x;
    int ns = min(*spillCnt, SPILL_CAP);
    if (e < ns) atomicAdd(&deg[spill[e].y], __int_as_float(spill[e].z));
}

__global__ void dinv_kernel(float* __restrict__ deg, int N) {
    int i = blockIdx.x * blockDim.x + threadIdx.x;
    if (i < N) {
        float d = deg[i];
        deg[i] = (d > 0.f) ? rsqrtf(d) : 0.f;
    }
}

// precompute norm_e = dinv[src]*w*dinv[dst] in place (.y); shared by both layers
__global__ __launch_bounds__(256) void norm_kernel(
    int2* __restrict__ bucket, const int* __restrict__ bucketCnt,
    const float* __restrict__ dinv)
{
    int b = blockIdx.x;
    int cnt = min(bucketCnt[b], BCAP);
    int2* seg = bucket + (size_t)b * BCAP;
    for (int i = threadIdx.x; i < cnt; i += 256) {
        int2 ed = seg[i];
        int src  = ed.x & SRCMASK;
        int dst  = (b << BSHIFT) + (ed.x >> SRCBITS);
        float nm = dinv[src] * __int_as_float(ed.y) * dinv[dst];
        seg[i] = make_int2(ed.x, __float_as_int(nm));
    }
}

// wave-per-node aggregation; two 32-lane halves each process one edge with
// float2 (8B) lane loads (round-11, proven 70.8 us)
__global__ __launch_bounds__(256) void agg2_kernel(
    const int* __restrict__ off, const int* __restrict__ ncnt, const int2* __restrict__ bucket,
    const float* __restrict__ hw, const float* __restrict__ dinv,
    const float* __restrict__ bias, float* __restrict__ hout, int N)
{
    int gid = blockIdx.x * blockDim.x + threadIdx.x;
    int n = gid >> 6, lane = gid & 63;
    if (n >= N) return;
    int half = lane >> 5;
    int l = lane & 31;
    int c = ncnt[n];
    const int2* row = bucket + off[n];
    const float2* hw2 = (const float2*)hw;

    float2 a0 = {0.f, 0.f}, a1 = {0.f, 0.f}, a2 = {0.f, 0.f}, a3 = {0.f, 0.f};
    int j = 0;
    for (; j + 7 < c; j += 8) {
        int2 e0 = row[j     + half];
        int2 e1 = row[j + 2 + half];
        int2 e2 = row[j + 4 + half];
        int2 e3 = row[j + 6 + half];
        float2 v0 = hw2[(size_t)(e0.x & SRCMASK) * 32 + l];
        float2 v1 = hw2[(size_t)(e1.x & SRCMASK) * 32 + l];
        float2 v2 = hw2[(size_t)(e2.x & SRCMASK) * 32 + l];
        float2 v3 = hw2[(size_t)(e3.x & SRCMASK) * 32 + l];
        float n0 = __int_as_float(e0.y), n1 = __int_as_float(e1.y);
        float n2 = __int_as_float(e2.y), n3 = __int_as_float(e3.y);
        a0.x += n0 * v0.x; a0.y += n0 * v0.y;
        a1.x += n1 * v1.x; a1.y += n1 * v1.y;
        a2.x += n2 * v2.x; a2.y += n2 * v2.y;
        a3.x += n3 * v3.x; a3.y += n3 * v3.y;
    }
    for (; j < c; j += 2) {
        int jj = j + half;
        if (jj < c) {
            int2 e0 = row[jj];
            float2 v0 = hw2[(size_t)(e0.x & SRCMASK) * 32 + l];
            float n0 = __int_as_float(e0.y);
            a0.x += n0 * v0.x; a0.y += n0 * v0.y;
        }
    }
    float Ax = (a0.x + a1.x) + (a2.x + a3.x);
    float Ay = (a0.y + a1.y) + (a2.y + a3.y);
    Ax += __shfl_xor(Ax, 32, 64);
    Ay += __shfl_xor(Ay, 32, 64);

    if (half == 0) {
        float dn = dinv[n];
        float2 self = hw2[(size_t)n * 32 + l];
        float2 bb = ((const float2*)bias)[l];
        float2 o;
        o.x = Ax + dn * dn * self.x + bb.x;
        o.y = Ay + dn * dn * self.y + bb.y;
        ((float2*)hout)[(size_t)n * 32 + l] = o;
    }
}

__global__ __launch_bounds__(256) void spill_agg_kernel(
    const int4* __restrict__ spill, const int* __restrict__ spillCnt,
    const float* __restrict__ hw, const float* __restrict__ dinv, float* __restrict__ hout)
{
    int gid = blockIdx.x * blockDim.x + threadIdx.x;
    int e = gid >> 6, lane = gid & 63;
    int ns = min(*spillCnt, SPILL_CAP);
    if (e >= ns) return;
    int4 sp = spill[e];
    float nm = dinv[sp.x] * __int_as_float(sp.z) * dinv[sp.y];
    atomicAdd(&hout[(size_t)sp.y * HDIM + lane], nm * hw[(size_t)sp.x * HDIM + lane]);
}

// ================= shared: GEMM (float4 LDS reads: 4x fewer LDS instructions) =================

template<int LAYER>
__global__ __launch_bounds__(256) void gemm_kernel(
    const float* __restrict__ x, const int* __restrict__ mapping,
    const float* __restrict__ emb, const float* __restrict__ hin,
    const float* __restrict__ W, float* __restrict__ hw, int N)
{
    __shared__ __align__(16) float ins[64][HDIM];   // 16 KB
    int t = threadIdx.x;
    int nodeBase = blockIdx.x * 64;

    // staging: one float4 per iteration (16 float4 per 64-float row)
    for (int i = t; i < 64 * 16; i += 256) {
        int nr = i >> 4, q = i & 15;
        int n = nodeBase + nr;
        float4 v4 = {0.f, 0.f, 0.f, 0.f};
        if (n < N) {
            if (LAYER == 0) {
                if (q < 8) v4 = ((const float4*)(x   + (size_t)n * NFEAT))[q];
                else       v4 = ((const float4*)(emb + (size_t)mapping[n] * NEMB))[q - 8];
            } else {
                float4 h4 = ((const float4*)(hin + (size_t)n * HDIM))[q];
                v4.x = fmaxf(h4.x, 0.f); v4.y = fmaxf(h4.y, 0.f);
                v4.z = fmaxf(h4.z, 0.f); v4.w = fmaxf(h4.w, 0.f);
            }
        }
        ((float4*)ins[nr])[q] = v4;
    }

    int k = t & 63;
    float wcol[HDIM];
    #pragma unroll
    for (int kk = 0; kk < HDIM; ++kk) wcol[kk] = W[kk * HDIM + k];
    __syncthreads();

    int nl = t >> 6;
    for (int ns = 0; ns < 16; ++ns) {
        int nrow = ns * 4 + nl;
        int n = nodeBase + nrow;
        float acc = 0.f;
        #pragma unroll
        for (int q = 0; q < 16; ++q) {
            float4 iv = ((const float4*)ins[nrow])[q];   // ds_read_b128 broadcast
            acc += iv.x * wcol[4*q]     + iv.y * wcol[4*q + 1]
                 + iv.z * wcol[4*q + 2] + iv.w * wcol[4*q + 3];
        }
        if (n < N) hw[(size_t)n * HDIM + k] = acc;
    }
}

// ================= tier 2: ELL path =================

__global__ void init_ell_kernel(int* __restrict__ cnt, int* __restrict__ spillCnt, int N) {
    int i = blockIdx.x * blockDim.x + threadIdx.x;
    if (i < N) cnt[i] = 0;
    if (i == 0) *spillCnt = 0;
}

__global__ void ell_fill_kernel(const int* __restrict__ ei, const float* __restrict__ ew,
                                int* __restrict__ cnt, int2* __restrict__ ell,
                                int4* __restrict__ spill, int* __restrict__ spillCnt, int E) {
    int e = blockIdx.x * blockDim.x + threadIdx.x;
    if (e >= E) return;
    int src = ei[e];
    int dst = ei[E + e];
    float w = ew[e];
    int slot = atomicAdd(&cnt[dst], 1);
    if (slot < MAXD) {
        ell[(size_t)dst * MAXD + slot] = make_int2(src, __float_as_int(w));
    } else {
        int sp = atomicAdd(spillCnt, 1);
        if (sp < SPILL_CAP) spill[sp] = make_int4(src, dst, __float_as_int(w), 0);
    }
}

__global__ __launch_bounds__(256) void degsum_kernel(const int2* __restrict__ ell,
                                                     const int* __restrict__ cnt,
                                                     float* __restrict__ deg, int N) {
    int gid = blockIdx.x * blockDim.x + threadIdx.x;
    int n = gid >> 6, lane = gid & 63;
    if (n >= N) return;
    int c = min(cnt[n], MAXD);
    float s = (lane < c) ? __int_as_float(ell[(size_t)n * MAXD + lane].y) : 0.f;
    #pragma unroll
    for (int d = 32; d > 0; d >>= 1) s += __shfl_down(s, d, 64);
    if (lane == 0) deg[n] = 1.f + s;
}

__global__ __launch_bounds__(256) void agg_kernel(
    const int2* __restrict__ ell, const int* __restrict__ cnt,
    const float* __restrict__ hw, const float* __restrict__ dinv,
    const float* __restrict__ bias, float* __restrict__ hout, int N)
{
    int gid = blockIdx.x * blockDim.x + threadIdx.x;
    int n = gid >> 6, lane = gid & 63;
    if (n >= N) return;
    int c = min(cnt[n], MAXD);
    const int2* row = ell + (size_t)n * MAXD;
    float acc0 = 0.f, acc1 = 0.f;
    int j = 0;
    for (; j + 1 < c; j += 2) {
        int2 e0 = row[j], e1 = row[j + 1];
        acc0 += dinv[e0.x] * __int_as_float(e0.y) * hw[(size_t)e0.x * HDIM + lane];
        acc1 += dinv[e1.x] * __int_as_float(e1.y) * hw[(size_t)e1.x * HDIM + lane];
    }
    if (j < c) {
        int2 e0 = row[j];
        acc0 += dinv[e0.x] * __int_as_float(e0.y) * hw[(size_t)e0.x * HDIM + lane];
    }
    float dn = dinv[n];
    hout[(size_t)n * HDIM + lane] =
        dn * (acc0 + acc1) + dn * dn * hw[(size_t)n * HDIM + lane] + bias[lane];
}

// ================= tier 3: atomic scatter =================

__global__ void init_kernel(float* __restrict__ deg, int* __restrict__ cnt, int N) {
    int i = blockIdx.x * blockDim.x + threadIdx.x;
    if (i < N) { deg[i] = 1.0f; cnt[i] = 0; }
}

__global__ void hist_kernel(const int* __restrict__ ei, const float* __restrict__ ew,
                            float* __restrict__ deg, int* __restrict__ cnt, int E) {
    int e = blockIdx.x * blockDim.x + threadIdx.x;
    if (e < E) {
        int dst = ei[E + e];
        atomicAdd(&deg[dst], ew[e]);
        atomicAdd(&cnt[dst], 1);
    }
}

__global__ void self_init_kernel(const float* __restrict__ hw, const float* __restrict__ dinv,
                                 const float* __restrict__ b, float* __restrict__ hout, int NF) {
    int i = blockIdx.x * blockDim.x + threadIdx.x;
    if (i < NF) {
        int n = i >> 6, f = i & 63;
        float di = dinv[n];
        hout[i] = b[f] + di * di * hw[i];
    }
}

__global__ __launch_bounds__(256) void scatter_kernel(
    const int* __restrict__ ei, const float* __restrict__ ew,
    const float* __restrict__ dinv, const float* __restrict__ hw,
    float* __restrict__ hout, int E)
{
    int gid = blockIdx.x * blockDim.x + threadIdx.x;
    int e = gid >> 5, lane = gid & 31;
    if (e >= E) return;
    int src = ei[e];
    int dst = ei[E + e];
    float norm = dinv[src] * ew[e] * dinv[dst];
    float2 v = ((const float2*)hw)[(size_t)src * (HDIM / 2) + lane];
    float* o = &hout[(size_t)dst * HDIM + 2 * lane];
    atomicAdd(o,     norm * v.x);
    atomicAdd(o + 1, norm * v.y);
}

// ================= pooling: POOLSPLIT blocks per graph + atomic merge =================

__global__ void zero_out_kernel(float* __restrict__ out) {
    int i = blockIdx.x * blockDim.x + threadIdx.x;
    if (i < GBATCH * HDIM) out[i] = 0.f;
}

__global__ __launch_bounds__(256) void pool_kernel(
    const float* __restrict__ h, const int* __restrict__ batch,
    float* __restrict__ out, int N)
{
    int g = blockIdx.x / POOLSPLIT;
    int slice = blockIdx.x % POOLSPLIT;
    int t = threadIdx.x;
    int lane = t & 63, w = t >> 6;

    int lo = 0, hi = N;
    while (lo < hi) { int m = (lo + hi) >> 1; if (batch[m] < g) lo = m + 1; else hi = m; }
    int start = lo;
    hi = N;
    while (lo < hi) { int m = (lo + hi) >> 1; if (batch[m] < g + 1) lo = m + 1; else hi = m; }
    int end = lo;

    float acc = 0.f;
    for (int n = start + slice * 4 + w; n < end; n += POOLSPLIT * 4)
        acc += fmaxf(h[(size_t)n * HDIM + lane], 0.f);

    __shared__ float red[4][HDIM];
    red[w][lane] = acc;
    __syncthreads();
    if (w == 0) {
        float s = red[0][lane] + red[1][lane] + red[2][lane] + red[3][lane];
        if (s != 0.f || slice == 0) atomicAdd(&out[g * HDIM + lane], s);
    }
}

__global__ void div_kernel(float* __restrict__ out, const int* __restrict__ batch, int N) {
    int i = blockIdx.x * blockDim.x + threadIdx.x;
    if (i >= GBATCH * HDIM) return;
    int g = i >> 6;
    int lo = 0, hi = N;
    while (lo < hi) { int m = (lo + hi) >> 1; if (batch[m] < g) lo = m + 1; else hi = m; }
    int start = lo;
    hi = N;
    while (lo < hi) { int m = (lo + hi) >> 1; if (batch[m] < g + 1) lo = m + 1; else hi = m; }
    float c = (float)(lo - start);
    out[i] /= fmaxf(c, 1.f);
}

// ================= launch =================

extern "C" void kernel_launch(void* const* d_in, const int* in_sizes, int n_in,
                              void* d_out, int out_size, void* d_ws, size_t ws_size,
                              hipStream_t stream) {
    const float* x       = (const float*)d_in[0];
    const int*   mapping = (const int*)  d_in[1];
    const int*   ei      = (const int*)  d_in[2];
    const float* ew      = (const float*)d_in[3];
    const int*   batch   = (const int*)  d_in[4];
    const float* emb     = (const float*)d_in[5];
    const float* W0      = (const float*)d_in[6];
    const float* b0      = (const float*)d_in[7];
    const float* W1      = (const float*)d_in[8];
    const float* b1      = (const float*)d_in[9];
    float* out = (float*)d_out;

    const int N = in_sizes[1];
    const int E = in_sizes[2] / 2;

    const int gemmGrid = (N + 63) / 64;
    const int nodeGrid = (N * 64 + 255) / 256;
    const int spillGrid = (SPILL_CAP * 64 + 255) / 256;

    size_t need_part = (size_t)NBUCK * BCAP * 8 + (size_t)N * HDIM * 4 * 2 + (size_t)N * 4 * 3
                     + (size_t)NBUCK * 4 + (size_t)SPILL_CAP * 16 + 16;
    size_t need_ell = (size_t)N * MAXD * 8 + (size_t)N * HDIM * 4 * 2 + (size_t)N * 4 * 2
                    + (size_t)SPILL_CAP * 16 + 16;

    if (ws_size >= need_part && N <= (NBUCK << BSHIFT) && N <= (1 << SRCBITS)) {
        char* p = (char*)d_ws;
        int2*  bucket    = (int2*)p;           p += (size_t)NBUCK * BCAP * 8;
        float* bufA      = (float*)p;          p += (size_t)N * HDIM * 4;
        float* bufB      = (float*)p;          p += (size_t)N * HDIM * 4;
        float* deg       = (float*)p;          p += (size_t)N * 4;
        int*   off       = (int*)p;            p += (size_t)N * 4;
        int*   ncnt      = (int*)p;            p += (size_t)N * 4;
        int*   bucketCnt = (int*)p;            p += (size_t)NBUCK * 4;
        int4*  spill     = (int4*)p;           p += (size_t)SPILL_CAP * 16;
        int*   spillCnt  = (int*)p;

        const int nChunks = (E + CHUNK - 1) / CHUNK;

        zero_part_kernel<<<(NBUCK + 255) / 256, 256, 0, stream>>>(bucketCnt, spillCnt);
        partition_kernel<<<nChunks, PBLOCK, 0, stream>>>(ei, ew, bucketCnt, bucket, spill, spillCnt, E);
        localsort_kernel<<<NBUCK, 256, 0, stream>>>(bucket, bucketCnt, off, ncnt, deg, N);
        spill_deg_kernel<<<(SPILL_CAP + 255) / 256, 256, 0, stream>>>(spill, spillCnt, deg);
        dinv_kernel<<<(N + 255) / 256, 256, 0, stream>>>(deg, N);
        norm_kernel<<<NBUCK, 256, 0, stream>>>(bucket, bucketCnt, deg);

        gemm_kernel<0><<<gemmGrid, 256, 0, stream>>>(x, mapping, emb, nullptr, W0, bufA, N);
        agg2_kernel<<<nodeGrid, 256, 0, stream>>>(off, ncnt, bucket, bufA, deg, b0, bufB, N);
        spill_agg_kernel<<<spillGrid, 256, 0, stream>>>(spill, spillCnt, bufA, deg, bufB);

        gemm_kernel<1><<<gemmGrid, 256, 0, stream>>>(nullptr, nullptr, nullptr, bufB, W1, bufA, N);
        agg2_kernel<<<nodeGrid, 256, 0, stream>>>(off, ncnt, bucket, bufA, deg, b1, bufB, N);
        spill_agg_kernel<<<spillGrid, 256, 0, stream>>>(spill, spillCnt, bufA, deg, bufB);

        zero_out_kernel<<<(GBATCH * HDIM + 255) / 256, 256, 0, stream>>>(out);
        pool_kernel<<<GBATCH * POOLSPLIT, 256, 0, stream>>>(bufB, batch, out, N);
        div_kernel<<<(GBATCH * HDIM + 255) / 256, 256, 0, stream>>>(out, batch, N);
    } else if (ws_size >= need_ell) {
        char* p = (char*)d_ws;
        int2*  ell  = (int2*)p;                p += (size_t)N * MAXD * 8;
        float* bufA = (float*)p;               p += (size_t)N * HDIM * 4;
        float* bufB = (float*)p;               p += (size_t)N * HDIM * 4;
        float* deg  = (float*)p;               p += (size_t)N * 4;
        int*   cnt  = (int*)p;                 p += (size_t)N * 4;
        int4*  spill = (int4*)p;               p += (size_t)SPILL_CAP * 16;
        int*   spillCnt = (int*)p;

        init_ell_kernel<<<(N + 255) / 256, 256, 0, stream>>>(cnt, spillCnt, N);
        ell_fill_kernel<<<(E + 255) / 256, 256, 0, stream>>>(ei, ew, cnt, ell, spill, spillCnt, E);
        degsum_kernel<<<nodeGrid, 256, 0, stream>>>(ell, cnt, deg, N);
        spill_deg_kernel<<<(SPILL_CAP + 255) / 256, 256, 0, stream>>>(spill, spillCnt, deg);
        dinv_kernel<<<(N + 255) / 256, 256, 0, stream>>>(deg, N);

        gemm_kernel<0><<<gemmGrid, 256, 0, stream>>>(x, mapping, emb, nullptr, W0, bufA, N);
        agg_kernel<<<nodeGrid, 256, 0, stream>>>(ell, cnt, bufA, deg, b0, bufB, N);
        spill_agg_kernel<<<spillGrid, 256, 0, stream>>>(spill, spillCnt, bufA, deg, bufB);

        gemm_kernel<1><<<gemmGrid, 256, 0, stream>>>(nullptr, nullptr, nullptr, bufB, W1, bufA, N);
        agg_kernel<<<nodeGrid, 256, 0, stream>>>(ell, cnt, bufA, deg, b1, bufB, N);
        spill_agg_kernel<<<spillGrid, 256, 0, stream>>>(spill, spillCnt, bufA, deg, bufB);

        zero_out_kernel<<<(GBATCH * HDIM + 255) / 256, 256, 0, stream>>>(out);
        pool_kernel<<<GBATCH * POOLSPLIT, 256, 0, stream>>>(bufB, batch, out, N);
        div_kernel<<<(GBATCH * HDIM + 255) / 256, 256, 0, stream>>>(out, batch, N);
    } else {
        char* p = (char*)d_ws;
        float* bufA = (float*)p;               p += (size_t)N * HDIM * 4;
        float* bufB = (float*)p;               p += (size_t)N * HDIM * 4;
        float* deg  = (float*)p;               p += (size_t)N * 4;
        int*   cnt  = (int*)p;

        const int NF = N * HDIM;
        const int scatGrid = (E * 32 + 255) / 256;
        init_kernel<<<(N + 255) / 256, 256, 0, stream>>>(deg, cnt, N);
        hist_kernel<<<(E + 255) / 256, 256, 0, stream>>>(ei, ew, deg, cnt, E);
        dinv_kernel<<<(N + 255) / 256, 256, 0, stream>>>(deg, N);

        gemm_kernel<0><<<gemmGrid, 256, 0, stream>>>(x, mapping, emb, nullptr, W0, bufA, N);
        self_init_kernel<<<(NF + 255) / 256, 256, 0, stream>>>(bufA, deg, b0, bufB, NF);
        scatter_kernel<<<scatGrid, 256, 0, stream>>>(ei, ew, deg, bufA, bufB, E);

        gemm_kernel<1><<<gemmGrid, 256, 0, stream>>>(nullptr, nullptr, nullptr, bufB, W1, bufA, N);
        self_init_kernel<<<(NF + 255) / 256, 256, 0, stream>>>(bufA, deg, b1, bufB, NF);
        scatter_kernel<<<scatGrid, 256, 0, stream>>>(ei, ew, deg, bufA, bufB, E);

        zero_out_kernel<<<(GBATCH * HDIM + 255) / 256, 256, 0, stream>>>(out);
        pool_kernel<<<GBATCH * POOLSPLIT, 256, 0, stream>>>(bufB, batch, out, N);
        div_kernel<<<(GBATCH * HDIM + 255) / 256, 256, 0, stream>>>(out, batch, N);
    }
}

// Round 15
// 351.867 us; speedup vs baseline: 15.1251x; 1.0734x over previous
//
#include <hip/hip_runtime.h>

#define HDIM 64
#define NFEAT 32
#define NEMB 32
#define GBATCH 128
#define MAXD 48
#define SPILL_CAP 4096
#define POOLSPLIT 8

// partition path
#define NBUCK 1024
#define BSHIFT 7                 // 128 nodes per bucket
#define BNODES (1 << BSHIFT)
#define BCAP 2048
#define CHUNK 6144
#define PBLOCK 1024
#define EPT (CHUNK / PBLOCK)     // 6 edges per thread
#define SRCBITS 20
#define SRCMASK ((1 << SRCBITS) - 1)

__device__ __forceinline__ float bf16_to_f(unsigned short u) {
    return __uint_as_float((unsigned int)u << 16);
}
__device__ __forceinline__ unsigned short f_to_bf16(float f) {   // RTNE
    unsigned int u = __float_as_uint(f);
    return (unsigned short)((u + 0x7FFFu + ((u >> 16) & 1u)) >> 16);
}

// ================= tier 1: partition + bucket-local CSR =================

__global__ void zero_part_kernel(int* __restrict__ bucketCnt, int* __restrict__ spillCnt) {
    int i = blockIdx.x * blockDim.x + threadIdx.x;
    if (i < NBUCK) bucketCnt[i] = 0;
    if (i == 0) *spillCnt = 0;
}

// LDS-staged partition (round-13, proven): shfl hierarchical scan, 3 barriers
__global__ __launch_bounds__(PBLOCK) void partition_kernel(
    const int* __restrict__ ei, const float* __restrict__ ew,
    int* __restrict__ bucketCnt, int2* __restrict__ bucket,
    int4* __restrict__ spill, int* __restrict__ spillCnt, int E)
{
    __shared__ int2 stage[CHUNK];   // 48 KB
    __shared__ int hist[NBUCK];     // 4 KB
    __shared__ int cursor[NBUCK];   // 4 KB
    __shared__ int gbase[NBUCK];    // 4 KB
    __shared__ int wsum[16];

    int t = threadIdx.x;
    int c0 = blockIdx.x * CHUNK;
    if (c0 >= E) return;
    int nE = min(CHUNK, E - c0);

    hist[t] = 0;                    // NBUCK == PBLOCK
    __syncthreads();

    int2 re[EPT];
    int  rb[EPT];
    #pragma unroll
    for (int j = 0; j < EPT; ++j) {
        int i = t + j * PBLOCK;
        if (i < nE) {
            int src = ei[c0 + i];
            int d   = ei[E + c0 + i];
            float w = ew[c0 + i];
            int b = d >> BSHIFT;
            re[j] = make_int2(src | ((d & (BNODES - 1)) << SRCBITS), __float_as_int(w));
            rb[j] = b;
            atomicAdd(&hist[b], 1);
        } else {
            rb[j] = -1;
        }
    }
    __syncthreads();

    int s = hist[t];
    int v = s;
    #pragma unroll
    for (int d = 1; d < 64; d <<= 1) {
        int u = __shfl_up(v, d, 64);
        if ((t & 63) >= d) v += u;
    }
    if ((t & 63) == 63) wsum[t >> 6] = v;
    __syncthreads();
    if (t == 0) {
        int acc = 0;
        #pragma unroll
        for (int i = 0; i < 16; ++i) { int xx = wsum[i]; wsum[i] = acc; acc += xx; }
    }
    __syncthreads();
    cursor[t] = v - s + wsum[t >> 6];
    gbase[t]  = (s > 0) ? atomicAdd(&bucketCnt[t], s) : 0;
    __syncthreads();

    #pragma unroll
    for (int j = 0; j < EPT; ++j) {
        if (rb[j] >= 0) {
            int pos = atomicAdd(&cursor[rb[j]], 1);
            stage[pos] = re[j];
        }
    }
    __syncthreads();

    int wid = t >> 6, lane = t & 63;
    for (int b = wid; b < NBUCK; b += (PBLOCK / 64)) {
        int h = hist[b];
        if (h == 0) continue;
        int lbase = cursor[b] - h;
        int gb = gbase[b];
        for (int k = lane; k < h; k += 64) {
            int2 ed = stage[lbase + k];
            int gpos = gb + k;
            if (gpos < BCAP) {
                bucket[(size_t)b * BCAP + gpos] = ed;
            } else {
                int sp = atomicAdd(spillCnt, 1);
                if (sp < SPILL_CAP)
                    spill[sp] = make_int4(ed.x & SRCMASK,
                                          (b << BSHIFT) + (ed.x >> SRCBITS), ed.y, 0);
            }
        }
    }
}

// in-LDS sort of each bucket into per-node contiguous runs (round-13, proven)
__global__ __launch_bounds__(256) void localsort_kernel(
    int2* __restrict__ bucket, const int* __restrict__ bucketCnt,
    int* __restrict__ off, int* __restrict__ ncnt, float* __restrict__ deg, int N)
{
    __shared__ int2 seg[BCAP];      // 16 KB
    __shared__ int2 sorted[BCAP];   // 16 KB
    __shared__ int h128[BNODES];
    __shared__ int sc[BNODES];
    __shared__ int cur[BNODES];
    __shared__ int wtot;

    int b = blockIdx.x;
    int t = threadIdx.x;
    int cnt = min(bucketCnt[b], BCAP);
    int2* gseg = bucket + (size_t)b * BCAP;

    for (int i = t; i < cnt; i += 256) seg[i] = gseg[i];
    if (t < BNODES) h128[t] = 0;
    __syncthreads();
    for (int i = t; i < cnt; i += 256)
        atomicAdd(&h128[seg[i].x >> SRCBITS], 1);
    __syncthreads();

    int s0 = 0, v = 0;
    if (t < BNODES) {
        s0 = h128[t];
        v = s0;
        #pragma unroll
        for (int d = 1; d < 64; d <<= 1) {
            int u = __shfl_up(v, d, 64);
            if ((t & 63) >= d) v += u;
        }
    }
    if (t == 63) wtot = v;
    __syncthreads();
    if (t >= 64 && t < BNODES) v += wtot;
    if (t < BNODES) { sc[t] = v; cur[t] = v - s0; }
    __syncthreads();

    for (int i = t; i < cnt; i += 256) {
        int dlow = seg[i].x >> SRCBITS;
        int p = atomicAdd(&cur[dlow], 1);
        sorted[p] = seg[i];
    }
    __syncthreads();

    for (int i = t; i < cnt; i += 256) gseg[i] = sorted[i];

    if (t < BNODES) {
        int n = (b << BSHIFT) + t;
        if (n < N) {
            int st = sc[t] - h128[t];
            int c  = h128[t];
            float s = 1.0f;                      // self-loop weight
            for (int j = 0; j < c; ++j) s += __int_as_float(sorted[st + j].y);
            off[n]  = b * BCAP + st;
            ncnt[n] = c;
            deg[n]  = s;
        }
    }
}

__global__ void spill_deg_kernel(const int4* __restrict__ spill, const int* __restrict__ spillCnt,
                                 float* __restrict__ deg) {
    int e = blockIdx.x * blockDim.x + threadIdx.x;
    int ns = min(*spillCnt, SPILL_CAP);
    if (e < ns) atomicAdd(&deg[spill[e].y], __int_as_float(spill[e].z));
}

__global__ void dinv_kernel(float* __restrict__ deg, int N) {
    int i = blockIdx.x * blockDim.x + threadIdx.x;
    if (i < N) {
        float d = deg[i];
        deg[i] = (d > 0.f) ? rsqrtf(d) : 0.f;
    }
}

// precompute norm_e = dinv[src]*w*dinv[dst] in place (.y)
__global__ __launch_bounds__(256) void norm_kernel(
    int2* __restrict__ bucket, const int* __restrict__ bucketCnt,
    const float* __restrict__ dinv)
{
    int b = blockIdx.x;
    int cnt = min(bucketCnt[b], BCAP);
    int2* seg = bucket + (size_t)b * BCAP;
    for (int i = threadIdx.x; i < cnt; i += 256) {
        int2 ed = seg[i];
        int src  = ed.x & SRCMASK;
        int dst  = (b << BSHIFT) + (ed.x >> SRCBITS);
        float nm = dinv[src] * __int_as_float(ed.y) * dinv[dst];
        seg[i] = make_int2(ed.x, __float_as_int(nm));
    }
}

// wave-per-node aggregation; edge gathers from bf16 copy (128B rows, half the
// cache lines of fp32); self term from exact fp32 copy.
__global__ __launch_bounds__(256) void agg2_kernel(
    const int* __restrict__ off, const int* __restrict__ ncnt, const int2* __restrict__ bucket,
    const float* __restrict__ hw, const unsigned short* __restrict__ hw16,
    const float* __restrict__ dinv,
    const float* __restrict__ bias, float* __restrict__ hout, int N)
{
    int gid = blockIdx.x * blockDim.x + threadIdx.x;
    int n = gid >> 6, lane = gid & 63;
    if (n >= N) return;
    int half = lane >> 5;
    int l = lane & 31;
    int c = ncnt[n];
    const int2* row = bucket + off[n];
    const ushort2* hwb = (const ushort2*)hw16;   // index: src*32 + l -> feats 2l,2l+1

    float2 a0 = {0.f, 0.f}, a1 = {0.f, 0.f}, a2 = {0.f, 0.f}, a3 = {0.f, 0.f};
    int j = 0;
    for (; j + 7 < c; j += 8) {
        int2 e0 = row[j     + half];
        int2 e1 = row[j + 2 + half];
        int2 e2 = row[j + 4 + half];
        int2 e3 = row[j + 6 + half];
        ushort2 u0 = hwb[(size_t)(e0.x & SRCMASK) * 32 + l];
        ushort2 u1 = hwb[(size_t)(e1.x & SRCMASK) * 32 + l];
        ushort2 u2 = hwb[(size_t)(e2.x & SRCMASK) * 32 + l];
        ushort2 u3 = hwb[(size_t)(e3.x & SRCMASK) * 32 + l];
        float n0 = __int_as_float(e0.y), n1 = __int_as_float(e1.y);
        float n2 = __int_as_float(e2.y), n3 = __int_as_float(e3.y);
        a0.x += n0 * bf16_to_f(u0.x); a0.y += n0 * bf16_to_f(u0.y);
        a1.x += n1 * bf16_to_f(u1.x); a1.y += n1 * bf16_to_f(u1.y);
        a2.x += n2 * bf16_to_f(u2.x); a2.y += n2 * bf16_to_f(u2.y);
        a3.x += n3 * bf16_to_f(u3.x); a3.y += n3 * bf16_to_f(u3.y);
    }
    for (; j < c; j += 2) {
        int jj = j + half;
        if (jj < c) {
            int2 e0 = row[jj];
            ushort2 u0 = hwb[(size_t)(e0.x & SRCMASK) * 32 + l];
            float n0 = __int_as_float(e0.y);
            a0.x += n0 * bf16_to_f(u0.x); a0.y += n0 * bf16_to_f(u0.y);
        }
    }
    float Ax = (a0.x + a1.x) + (a2.x + a3.x);
    float Ay = (a0.y + a1.y) + (a2.y + a3.y);
    Ax += __shfl_xor(Ax, 32, 64);
    Ay += __shfl_xor(Ay, 32, 64);

    if (half == 0) {
        float dn = dinv[n];
        float2 self = ((const float2*)hw)[(size_t)n * 32 + l];   // exact fp32 self term
        float2 bb = ((const float2*)bias)[l];
        float2 o;
        o.x = Ax + dn * dn * self.x + bb.x;
        o.y = Ay + dn * dn * self.y + bb.y;
        ((float2*)hout)[(size_t)n * 32 + l] = o;
    }
}

__global__ __launch_bounds__(256) void spill_agg_kernel(
    const int4* __restrict__ spill, const int* __restrict__ spillCnt,
    const float* __restrict__ hw, const float* __restrict__ dinv, float* __restrict__ hout)
{
    int gid = blockIdx.x * blockDim.x + threadIdx.x;
    int e = gid >> 6, lane = gid & 63;
    int ns = min(*spillCnt, SPILL_CAP);
    if (e >= ns) return;
    int4 sp = spill[e];
    float nm = dinv[sp.x] * __int_as_float(sp.z) * dinv[sp.y];
    atomicAdd(&hout[(size_t)sp.y * HDIM + lane], nm * hw[(size_t)sp.x * HDIM + lane]);
}

// ================= shared: GEMM (float4 LDS; dual fp32+bf16 output) =================

template<int LAYER>
__global__ __launch_bounds__(256) void gemm_kernel(
    const float* __restrict__ x, const int* __restrict__ mapping,
    const float* __restrict__ emb, const float* __restrict__ hin,
    const float* __restrict__ W, float* __restrict__ hw,
    unsigned short* __restrict__ hw16, int N)
{
    __shared__ __align__(16) float ins[64][HDIM];   // 16 KB
    int t = threadIdx.x;
    int nodeBase = blockIdx.x * 64;

    for (int i = t; i < 64 * 16; i += 256) {
        int nr = i >> 4, q = i & 15;
        int n = nodeBase + nr;
        float4 v4 = {0.f, 0.f, 0.f, 0.f};
        if (n < N) {
            if (LAYER == 0) {
                if (q < 8) v4 = ((const float4*)(x   + (size_t)n * NFEAT))[q];
                else       v4 = ((const float4*)(emb + (size_t)mapping[n] * NEMB))[q - 8];
            } else {
                float4 h4 = ((const float4*)(hin + (size_t)n * HDIM))[q];
                v4.x = fmaxf(h4.x, 0.f); v4.y = fmaxf(h4.y, 0.f);
                v4.z = fmaxf(h4.z, 0.f); v4.w = fmaxf(h4.w, 0.f);
            }
        }
        ((float4*)ins[nr])[q] = v4;
    }

    int k = t & 63;
    float wcol[HDIM];
    #pragma unroll
    for (int kk = 0; kk < HDIM; ++kk) wcol[kk] = W[kk * HDIM + k];
    __syncthreads();

    int nl = t >> 6;
    for (int ns = 0; ns < 16; ++ns) {
        int nrow = ns * 4 + nl;
        int n = nodeBase + nrow;
        float acc = 0.f;
        #pragma unroll
        for (int q = 0; q < 16; ++q) {
            float4 iv = ((const float4*)ins[nrow])[q];
            acc += iv.x * wcol[4*q]     + iv.y * wcol[4*q + 1]
                 + iv.z * wcol[4*q + 2] + iv.w * wcol[4*q + 3];
        }
        if (n < N) {
            hw[(size_t)n * HDIM + k] = acc;
            if (hw16) hw16[(size_t)n * HDIM + k] = f_to_bf16(acc);
        }
    }
}

// ================= tier 2: ELL path =================

__global__ void init_ell_kernel(int* __restrict__ cnt, int* __restrict__ spillCnt, int N) {
    int i = blockIdx.x * blockDim.x + threadIdx.x;
    if (i < N) cnt[i] = 0;
    if (i == 0) *spillCnt = 0;
}

__global__ void ell_fill_kernel(const int* __restrict__ ei, const float* __restrict__ ew,
                                int* __restrict__ cnt, int2* __restrict__ ell,
                                int4* __restrict__ spill, int* __restrict__ spillCnt, int E) {
    int e = blockIdx.x * blockDim.x + threadIdx.x;
    if (e >= E) return;
    int src = ei[e];
    int dst = ei[E + e];
    float w = ew[e];
    int slot = atomicAdd(&cnt[dst], 1);
    if (slot < MAXD) {
        ell[(size_t)dst * MAXD + slot] = make_int2(src, __float_as_int(w));
    } else {
        int sp = atomicAdd(spillCnt, 1);
        if (sp < SPILL_CAP) spill[sp] = make_int4(src, dst, __float_as_int(w), 0);
    }
}

__global__ __launch_bounds__(256) void degsum_kernel(const int2* __restrict__ ell,
                                                     const int* __restrict__ cnt,
                                                     float* __restrict__ deg, int N) {
    int gid = blockIdx.x * blockDim.x + threadIdx.x;
    int n = gid >> 6, lane = gid & 63;
    if (n >= N) return;
    int c = min(cnt[n], MAXD);
    float s = (lane < c) ? __int_as_float(ell[(size_t)n * MAXD + lane].y) : 0.f;
    #pragma unroll
    for (int d = 32; d > 0; d >>= 1) s += __shfl_down(s, d, 64);
    if (lane == 0) deg[n] = 1.f + s;
}

__global__ __launch_bounds__(256) void agg_kernel(
    const int2* __restrict__ ell, const int* __restrict__ cnt,
    const float* __restrict__ hw, const float* __restrict__ dinv,
    const float* __restrict__ bias, float* __restrict__ hout, int N)
{
    int gid = blockIdx.x * blockDim.x + threadIdx.x;
    int n = gid >> 6, lane = gid & 63;
    if (n >= N) return;
    int c = min(cnt[n], MAXD);
    const int2* row = ell + (size_t)n * MAXD;
    float acc0 = 0.f, acc1 = 0.f;
    int j = 0;
    for (; j + 1 < c; j += 2) {
        int2 e0 = row[j], e1 = row[j + 1];
        acc0 += dinv[e0.x] * __int_as_float(e0.y) * hw[(size_t)e0.x * HDIM + lane];
        acc1 += dinv[e1.x] * __int_as_float(e1.y) * hw[(size_t)e1.x * HDIM + lane];
    }
    if (j < c) {
        int2 e0 = row[j];
        acc0 += dinv[e0.x] * __int_as_float(e0.y) * hw[(size_t)e0.x * HDIM + lane];
    }
    float dn = dinv[n];
    hout[(size_t)n * HDIM + lane] =
        dn * (acc0 + acc1) + dn * dn * hw[(size_t)n * HDIM + lane] + bias[lane];
}

// ================= tier 3: atomic scatter =================

__global__ void init_kernel(float* __restrict__ deg, int* __restrict__ cnt, int N) {
    int i = blockIdx.x * blockDim.x + threadIdx.x;
    if (i < N) { deg[i] = 1.0f; cnt[i] = 0; }
}

__global__ void hist_kernel(const int* __restrict__ ei, const float* __restrict__ ew,
                            float* __restrict__ deg, int* __restrict__ cnt, int E) {
    int e = blockIdx.x * blockDim.x + threadIdx.x;
    if (e < E) {
        int dst = ei[E + e];
        atomicAdd(&deg[dst], ew[e]);
        atomicAdd(&cnt[dst], 1);
    }
}

__global__ void self_init_kernel(const float* __restrict__ hw, const float* __restrict__ dinv,
                                 const float* __restrict__ b, float* __restrict__ hout, int NF) {
    int i = blockIdx.x * blockDim.x + threadIdx.x;
    if (i < NF) {
        int n = i >> 6, f = i & 63;
        float di = dinv[n];
        hout[i] = b[f] + di * di * hw[i];
    }
}

__global__ __launch_bounds__(256) void scatter_kernel(
    const int* __restrict__ ei, const float* __restrict__ ew,
    const float* __restrict__ dinv, const float* __restrict__ hw,
    float* __restrict__ hout, int E)
{
    int gid = blockIdx.x * blockDim.x + threadIdx.x;
    int e = gid >> 5, lane = gid & 31;
    if (e >= E) return;
    int src = ei[e];
    int dst = ei[E + e];
    float norm = dinv[src] * ew[e] * dinv[dst];
    float2 v = ((const float2*)hw)[(size_t)src * (HDIM / 2) + lane];
    float* o = &hout[(size_t)dst * HDIM + 2 * lane];
    atomicAdd(o,     norm * v.x);
    atomicAdd(o + 1, norm * v.y);
}

// ================= pooling: POOLSPLIT blocks per graph + atomic merge =================

__global__ void zero_out_kernel(float* __restrict__ out) {
    int i = blockIdx.x * blockDim.x + threadIdx.x;
    if (i < GBATCH * HDIM) out[i] = 0.f;
}

__global__ __launch_bounds__(256) void pool_kernel(
    const float* __restrict__ h, const int* __restrict__ batch,
    float* __restrict__ out, int N)
{
    int g = blockIdx.x / POOLSPLIT;
    int slice = blockIdx.x % POOLSPLIT;
    int t = threadIdx.x;
    int lane = t & 63, w = t >> 6;

    int lo = 0, hi = N;
    while (lo < hi) { int m = (lo + hi) >> 1; if (batch[m] < g) lo = m + 1; else hi = m; }
    int start = lo;
    hi = N;
    while (lo < hi) { int m = (lo + hi) >> 1; if (batch[m] < g + 1) lo = m + 1; else hi = m; }
    int end = lo;

    float acc = 0.f;
    for (int n = start + slice * 4 + w; n < end; n += POOLSPLIT * 4)
        acc += fmaxf(h[(size_t)n * HDIM + lane], 0.f);

    __shared__ float red[4][HDIM];
    red[w][lane] = acc;
    __syncthreads();
    if (w == 0) {
        float s = red[0][lane] + red[1][lane] + red[2][lane] + red[3][lane];
        if (s != 0.f || slice == 0) atomicAdd(&out[g * HDIM + lane], s);
    }
}

__global__ void div_kernel(float* __restrict__ out, const int* __restrict__ batch, int N) {
    int i = blockIdx.x * blockDim.x + threadIdx.x;
    if (i >= GBATCH * HDIM) return;
    int g = i >> 6;
    int lo = 0, hi = N;
    while (lo < hi) { int m = (lo + hi) >> 1; if (batch[m] < g) lo = m + 1; else hi = m; }
    int start = lo;
    hi = N;
    while (lo < hi) { int m = (lo + hi) >> 1; if (batch[m] < g + 1) lo = m + 1; else hi = m; }
    float c = (float)(lo - start);
    out[i] /= fmaxf(c, 1.f);
}

// ================= launch =================

extern "C" void kernel_launch(void* const* d_in, const int* in_sizes, int n_in,
                              void* d_out, int out_size, void* d_ws, size_t ws_size,
                              hipStream_t stream) {
    const float* x       = (const float*)d_in[0];
    const int*   mapping = (const int*)  d_in[1];
    const int*   ei      = (const int*)  d_in[2];
    const float* ew      = (const float*)d_in[3];
    const int*   batch   = (const int*)  d_in[4];
    const float* emb     = (const float*)d_in[5];
    const float* W0      = (const float*)d_in[6];
    const float* b0      = (const float*)d_in[7];
    const float* W1      = (const float*)d_in[8];
    const float* b1      = (const float*)d_in[9];
    float* out = (float*)d_out;

    const int N = in_sizes[1];
    const int E = in_sizes[2] / 2;

    const int gemmGrid = (N + 63) / 64;
    const int nodeGrid = (N * 64 + 255) / 256;
    const int spillGrid = (SPILL_CAP * 64 + 255) / 256;

    // tier-1: bucket | bufA | bufB | bufA16 | deg | off | ncnt | bucketCnt | spill | spillCnt
    size_t need_part = (size_t)NBUCK * BCAP * 8 + (size_t)N * HDIM * 4 * 2
                     + (size_t)N * HDIM * 2
                     + (size_t)N * 4 * 3 + (size_t)NBUCK * 4 + (size_t)SPILL_CAP * 16 + 16;
    size_t need_ell = (size_t)N * MAXD * 8 + (size_t)N * HDIM * 4 * 2 + (size_t)N * 4 * 2
                    + (size_t)SPILL_CAP * 16 + 16;

    if (ws_size >= need_part && N <= (NBUCK << BSHIFT) && N <= (1 << SRCBITS)) {
        char* p = (char*)d_ws;
        int2*  bucket    = (int2*)p;           p += (size_t)NBUCK * BCAP * 8;
        float* bufA      = (float*)p;          p += (size_t)N * HDIM * 4;
        float* bufB      = (float*)p;          p += (size_t)N * HDIM * 4;
        unsigned short* bufA16 = (unsigned short*)p;  p += (size_t)N * HDIM * 2;
        float* deg       = (float*)p;          p += (size_t)N * 4;
        int*   off       = (int*)p;            p += (size_t)N * 4;
        int*   ncnt      = (int*)p;            p += (size_t)N * 4;
        int*   bucketCnt = (int*)p;            p += (size_t)NBUCK * 4;
        int4*  spill     = (int4*)p;           p += (size_t)SPILL_CAP * 16;
        int*   spillCnt  = (int*)p;

        const int nChunks = (E + CHUNK - 1) / CHUNK;

        zero_part_kernel<<<(NBUCK + 255) / 256, 256, 0, stream>>>(bucketCnt, spillCnt);
        partition_kernel<<<nChunks, PBLOCK, 0, stream>>>(ei, ew, bucketCnt, bucket, spill, spillCnt, E);
        localsort_kernel<<<NBUCK, 256, 0, stream>>>(bucket, bucketCnt, off, ncnt, deg, N);
        spill_deg_kernel<<<(SPILL_CAP + 255) / 256, 256, 0, stream>>>(spill, spillCnt, deg);
        dinv_kernel<<<(N + 255) / 256, 256, 0, stream>>>(deg, N);
        norm_kernel<<<NBUCK, 256, 0, stream>>>(bucket, bucketCnt, deg);

        gemm_kernel<0><<<gemmGrid, 256, 0, stream>>>(x, mapping, emb, nullptr, W0, bufA, bufA16, N);
        agg2_kernel<<<nodeGrid, 256, 0, stream>>>(off, ncnt, bucket, bufA, bufA16, deg, b0, bufB, N);
        spill_agg_kernel<<<spillGrid, 256, 0, stream>>>(spill, spillCnt, bufA, deg, bufB);

        gemm_kernel<1><<<gemmGrid, 256, 0, stream>>>(nullptr, nullptr, nullptr, bufB, W1, bufA, bufA16, N);
        agg2_kernel<<<nodeGrid, 256, 0, stream>>>(off, ncnt, bucket, bufA, bufA16, deg, b1, bufB, N);
        spill_agg_kernel<<<spillGrid, 256, 0, stream>>>(spill, spillCnt, bufA, deg, bufB);

        zero_out_kernel<<<(GBATCH * HDIM + 255) / 256, 256, 0, stream>>>(out);
        pool_kernel<<<GBATCH * POOLSPLIT, 256, 0, stream>>>(bufB, batch, out, N);
        div_kernel<<<(GBATCH * HDIM + 255) / 256, 256, 0, stream>>>(out, batch, N);
    } else if (ws_size >= need_ell) {
        char* p = (char*)d_ws;
        int2*  ell  = (int2*)p;                p += (size_t)N * MAXD * 8;
        float* bufA = (float*)p;               p += (size_t)N * HDIM * 4;
        float* bufB = (float*)p;               p += (size_t)N * HDIM * 4;
        float* deg  = (float*)p;               p += (size_t)N * 4;
        int*   cnt  = (int*)p;                 p += (size_t)N * 4;
        int4*  spill = (int4*)p;               p += (size_t)SPILL_CAP * 16;
        int*   spillCnt = (int*)p;

        init_ell_kernel<<<(N + 255) / 256, 256, 0, stream>>>(cnt, spillCnt, N);
        ell_fill_kernel<<<(E + 255) / 256, 256, 0, stream>>>(ei, ew, cnt, ell, spill, spillCnt, E);
        degsum_kernel<<<nodeGrid, 256, 0, stream>>>(ell, cnt, deg, N);
        spill_deg_kernel<<<(SPILL_CAP + 255) / 256, 256, 0, stream>>>(spill, spillCnt, deg);
        dinv_kernel<<<(N + 255) / 256, 256, 0, stream>>>(deg, N);

        gemm_kernel<0><<<gemmGrid, 256, 0, stream>>>(x, mapping, emb, nullptr, W0, bufA, nullptr, N);
        agg_kernel<<<nodeGrid, 256, 0, stream>>>(ell, cnt, bufA, deg, b0, bufB, N);
        spill_agg_kernel<<<spillGrid, 256, 0, stream>>>(spill, spillCnt, bufA, deg, bufB);

        gemm_kernel<1><<<gemmGrid, 256, 0, stream>>>(nullptr, nullptr, nullptr, bufB, W1, bufA, nullptr, N);
        agg_kernel<<<nodeGrid, 256, 0, stream>>>(ell, cnt, bufA, deg, b1, bufB, N);
        spill_agg_kernel<<<spillGrid, 256, 0, stream>>>(spill, spillCnt, bufA, deg, bufB);

        zero_out_kernel<<<(GBATCH * HDIM + 255) / 256, 256, 0, stream>>>(out);
        pool_kernel<<<GBATCH * POOLSPLIT, 256, 0, stream>>>(bufB, batch, out, N);
        div_kernel<<<(GBATCH * HDIM + 255) / 256, 256, 0, stream>>>(out, batch, N);
    } else {
        char* p = (char*)d_ws;
        float* bufA = (float*)p;               p += (size_t)N * HDIM * 4;
        float* bufB = (float*)p;               p += (size_t)N * HDIM * 4;
        float* deg  = (float*)p;               p += (size_t)N * 4;
        int*   cnt  = (int*)p;

        const int NF = N * HDIM;
        const int scatGrid = (E * 32 + 255) / 256;
        init_kernel<<<(N + 255) / 256, 256, 0, stream>>>(deg, cnt, N);
        hist_kernel<<<(E + 255) / 256, 256, 0, stream>>>(ei, ew, deg, cnt, E);
        dinv_kernel<<<(N + 255) / 256, 256, 0, stream>>>(deg, N);

        gemm_kernel<0><<<gemmGrid, 256, 0, stream>>>(x, mapping, emb, nullptr, W0, bufA, nullptr, N);
        self_init_kernel<<<(NF + 255) / 256, 256, 0, stream>>>(bufA, deg, b0, bufB, NF);
        scatter_kernel<<<scatGrid, 256, 0, stream>>>(ei, ew, deg, bufA, bufB, E);

        gemm_kernel<1><<<gemmGrid, 256, 0, stream>>>(nullptr, nullptr, nullptr, bufB, W1, bufA, nullptr, N);
        self_init_kernel<<<(NF + 255) / 256, 256, 0, stream>>>(bufA, deg, b1, bufB, NF);
        scatter_kernel<<<scatGrid, 256, 0, stream>>>(ei, ew, deg, bufA, bufB, E);

        zero_out_kernel<<<(GBATCH * HDIM + 255) / 256, 256, 0, stream>>>(out);
        pool_kernel<<<GBATCH * POOLSPLIT, 256, 0, stream>>>(bufB, batch, out, N);
        div_kernel<<<(GBATCH * HDIM + 255) / 256, 256, 0, stream>>>(out, batch, N);
    }
}

// Round 16
// 348.435 us; speedup vs baseline: 15.2741x; 1.0098x over previous
//
#include <hip/hip_runtime.h>

#define HDIM 64
#define NFEAT 32
#define NEMB 32
#define GBATCH 128
#define MAXD 48
#define SPILL_CAP 4096
#define POOLSPLIT 8

// partition path
#define NBUCK 1024
#define BSHIFT 7                 // 128 nodes per bucket
#define BNODES (1 << BSHIFT)
#define BCAP 2048
#define CHUNK 6144
#define PBLOCK 1024
#define EPT (CHUNK / PBLOCK)     // 6 edges per thread
#define SRCBITS 20
#define SRCMASK ((1 << SRCBITS) - 1)

__device__ __forceinline__ float bf16_to_f(unsigned short u) {
    return __uint_as_float((unsigned int)u << 16);
}
__device__ __forceinline__ unsigned short f_to_bf16(float f) {   // RTNE
    unsigned int u = __float_as_uint(f);
    return (unsigned short)((u + 0x7FFFu + ((u >> 16) & 1u)) >> 16);
}

// ================= tier 1: partition + bucket-local CSR =================

__global__ void zero_part_kernel(int* __restrict__ bucketCnt, int* __restrict__ spillCnt) {
    int i = blockIdx.x * blockDim.x + threadIdx.x;
    if (i < NBUCK) bucketCnt[i] = 0;
    if (i == 0) *spillCnt = 0;
}

// LDS-staged partition (round-13, proven): shfl hierarchical scan, 3 barriers
__global__ __launch_bounds__(PBLOCK) void partition_kernel(
    const int* __restrict__ ei, const float* __restrict__ ew,
    int* __restrict__ bucketCnt, int2* __restrict__ bucket,
    int4* __restrict__ spill, int* __restrict__ spillCnt, int E)
{
    __shared__ int2 stage[CHUNK];   // 48 KB
    __shared__ int hist[NBUCK];     // 4 KB
    __shared__ int cursor[NBUCK];   // 4 KB
    __shared__ int gbase[NBUCK];    // 4 KB
    __shared__ int wsum[16];

    int t = threadIdx.x;
    int c0 = blockIdx.x * CHUNK;
    if (c0 >= E) return;
    int nE = min(CHUNK, E - c0);

    hist[t] = 0;                    // NBUCK == PBLOCK
    __syncthreads();

    int2 re[EPT];
    int  rb[EPT];
    #pragma unroll
    for (int j = 0; j < EPT; ++j) {
        int i = t + j * PBLOCK;
        if (i < nE) {
            int src = ei[c0 + i];
            int d   = ei[E + c0 + i];
            float w = ew[c0 + i];
            int b = d >> BSHIFT;
            re[j] = make_int2(src | ((d & (BNODES - 1)) << SRCBITS), __float_as_int(w));
            rb[j] = b;
            atomicAdd(&hist[b], 1);
        } else {
            rb[j] = -1;
        }
    }
    __syncthreads();

    int s = hist[t];
    int v = s;
    #pragma unroll
    for (int d = 1; d < 64; d <<= 1) {
        int u = __shfl_up(v, d, 64);
        if ((t & 63) >= d) v += u;
    }
    if ((t & 63) == 63) wsum[t >> 6] = v;
    __syncthreads();
    if (t == 0) {
        int acc = 0;
        #pragma unroll
        for (int i = 0; i < 16; ++i) { int xx = wsum[i]; wsum[i] = acc; acc += xx; }
    }
    __syncthreads();
    cursor[t] = v - s + wsum[t >> 6];
    gbase[t]  = (s > 0) ? atomicAdd(&bucketCnt[t], s) : 0;
    __syncthreads();

    #pragma unroll
    for (int j = 0; j < EPT; ++j) {
        if (rb[j] >= 0) {
            int pos = atomicAdd(&cursor[rb[j]], 1);
            stage[pos] = re[j];
        }
    }
    __syncthreads();

    int wid = t >> 6, lane = t & 63;
    for (int b = wid; b < NBUCK; b += (PBLOCK / 64)) {
        int h = hist[b];
        if (h == 0) continue;
        int lbase = cursor[b] - h;
        int gb = gbase[b];
        for (int k = lane; k < h; k += 64) {
            int2 ed = stage[lbase + k];
            int gpos = gb + k;
            if (gpos < BCAP) {
                bucket[(size_t)b * BCAP + gpos] = ed;
            } else {
                int sp = atomicAdd(spillCnt, 1);
                if (sp < SPILL_CAP)
                    spill[sp] = make_int4(ed.x & SRCMASK,
                                          (b << BSHIFT) + (ed.x >> SRCBITS), ed.y, 0);
            }
        }
    }
}

// in-LDS sort of each bucket into per-node contiguous runs (round-13, proven)
__global__ __launch_bounds__(256) void localsort_kernel(
    int2* __restrict__ bucket, const int* __restrict__ bucketCnt,
    int* __restrict__ off, int* __restrict__ ncnt, float* __restrict__ deg, int N)
{
    __shared__ int2 seg[BCAP];      // 16 KB
    __shared__ int2 sorted[BCAP];   // 16 KB
    __shared__ int h128[BNODES];
    __shared__ int sc[BNODES];
    __shared__ int cur[BNODES];
    __shared__ int wtot;

    int b = blockIdx.x;
    int t = threadIdx.x;
    int cnt = min(bucketCnt[b], BCAP);
    int2* gseg = bucket + (size_t)b * BCAP;

    for (int i = t; i < cnt; i += 256) seg[i] = gseg[i];
    if (t < BNODES) h128[t] = 0;
    __syncthreads();
    for (int i = t; i < cnt; i += 256)
        atomicAdd(&h128[seg[i].x >> SRCBITS], 1);
    __syncthreads();

    int s0 = 0, v = 0;
    if (t < BNODES) {
        s0 = h128[t];
        v = s0;
        #pragma unroll
        for (int d = 1; d < 64; d <<= 1) {
            int u = __shfl_up(v, d, 64);
            if ((t & 63) >= d) v += u;
        }
    }
    if (t == 63) wtot = v;
    __syncthreads();
    if (t >= 64 && t < BNODES) v += wtot;
    if (t < BNODES) { sc[t] = v; cur[t] = v - s0; }
    __syncthreads();

    for (int i = t; i < cnt; i += 256) {
        int dlow = seg[i].x >> SRCBITS;
        int p = atomicAdd(&cur[dlow], 1);
        sorted[p] = seg[i];
    }
    __syncthreads();

    for (int i = t; i < cnt; i += 256) gseg[i] = sorted[i];

    if (t < BNODES) {
        int n = (b << BSHIFT) + t;
        if (n < N) {
            int st = sc[t] - h128[t];
            int c  = h128[t];
            float s = 1.0f;                      // self-loop weight
            for (int j = 0; j < c; ++j) s += __int_as_float(sorted[st + j].y);
            off[n]  = b * BCAP + st;
            ncnt[n] = c;
            deg[n]  = s;
        }
    }
}

__global__ void spill_deg_kernel(const int4* __restrict__ spill, const int* __restrict__ spillCnt,
                                 float* __restrict__ deg) {
    int e = blockIdx.x * blockDim.x + threadIdx.x;
    int ns = min(*spillCnt, SPILL_CAP);
    if (e < ns) atomicAdd(&deg[spill[e].y], __int_as_float(spill[e].z));
}

__global__ void dinv_kernel(float* __restrict__ deg, int N) {
    int i = blockIdx.x * blockDim.x + threadIdx.x;
    if (i < N) {
        float d = deg[i];
        deg[i] = (d > 0.f) ? rsqrtf(d) : 0.f;
    }
}

// precompute norm_e = dinv[src]*w*dinv[dst] in place (.y)
__global__ __launch_bounds__(256) void norm_kernel(
    int2* __restrict__ bucket, const int* __restrict__ bucketCnt,
    const float* __restrict__ dinv)
{
    int b = blockIdx.x;
    int cnt = min(bucketCnt[b], BCAP);
    int2* seg = bucket + (size_t)b * BCAP;
    for (int i = threadIdx.x; i < cnt; i += 256) {
        int2 ed = seg[i];
        int src  = ed.x & SRCMASK;
        int dst  = (b << BSHIFT) + (ed.x >> SRCBITS);
        float nm = dinv[src] * __int_as_float(ed.y) * dinv[dst];
        seg[i] = make_int2(ed.x, __float_as_int(nm));
    }
}

// wave-per-node aggregation; 16 lanes per edge, ushort4 (8B) bf16 loads.
// 4 edges per wave instruction, 4-deep unroll = 16 edges in flight.
__global__ __launch_bounds__(256) void agg2_kernel(
    const int* __restrict__ off, const int* __restrict__ ncnt, const int2* __restrict__ bucket,
    const float* __restrict__ hw, const unsigned short* __restrict__ hw16,
    const float* __restrict__ dinv,
    const float* __restrict__ bias, float* __restrict__ hout, int N)
{
    int gid = blockIdx.x * blockDim.x + threadIdx.x;
    int n = gid >> 6, lane = gid & 63;
    if (n >= N) return;
    int q = lane >> 4;             // edge slot 0..3
    int l = lane & 15;             // feature quad: feats 4l..4l+3
    int c = ncnt[n];
    const int2* row = bucket + off[n];
    const ushort4* hwb = (const ushort4*)hw16;   // row index: src*16 + l

    float4 a0 = {0,0,0,0}, a1 = {0,0,0,0}, a2 = {0,0,0,0}, a3 = {0,0,0,0};
    int j = 0;
    for (; j + 15 < c; j += 16) {  // 16 edges: 4 per slot, no bounds checks
        int2 e0 = row[j      + q];
        int2 e1 = row[j + 4  + q];
        int2 e2 = row[j + 8  + q];
        int2 e3 = row[j + 12 + q];
        ushort4 u0 = hwb[(size_t)(e0.x & SRCMASK) * 16 + l];
        ushort4 u1 = hwb[(size_t)(e1.x & SRCMASK) * 16 + l];
        ushort4 u2 = hwb[(size_t)(e2.x & SRCMASK) * 16 + l];
        ushort4 u3 = hwb[(size_t)(e3.x & SRCMASK) * 16 + l];
        float n0 = __int_as_float(e0.y), n1 = __int_as_float(e1.y);
        float n2 = __int_as_float(e2.y), n3 = __int_as_float(e3.y);
        a0.x += n0 * bf16_to_f(u0.x); a0.y += n0 * bf16_to_f(u0.y);
        a0.z += n0 * bf16_to_f(u0.z); a0.w += n0 * bf16_to_f(u0.w);
        a1.x += n1 * bf16_to_f(u1.x); a1.y += n1 * bf16_to_f(u1.y);
        a1.z += n1 * bf16_to_f(u1.z); a1.w += n1 * bf16_to_f(u1.w);
        a2.x += n2 * bf16_to_f(u2.x); a2.y += n2 * bf16_to_f(u2.y);
        a2.z += n2 * bf16_to_f(u2.z); a2.w += n2 * bf16_to_f(u2.w);
        a3.x += n3 * bf16_to_f(u3.x); a3.y += n3 * bf16_to_f(u3.y);
        a3.z += n3 * bf16_to_f(u3.z); a3.w += n3 * bf16_to_f(u3.w);
    }
    for (; j < c; j += 4) {        // predicated tail, 4 edges per step
        int jj = j + q;
        if (jj < c) {
            int2 e0 = row[jj];
            ushort4 u0 = hwb[(size_t)(e0.x & SRCMASK) * 16 + l];
            float n0 = __int_as_float(e0.y);
            a0.x += n0 * bf16_to_f(u0.x); a0.y += n0 * bf16_to_f(u0.y);
            a0.z += n0 * bf16_to_f(u0.z); a0.w += n0 * bf16_to_f(u0.w);
        }
    }
    float4 A;
    A.x = (a0.x + a1.x) + (a2.x + a3.x);
    A.y = (a0.y + a1.y) + (a2.y + a3.y);
    A.z = (a0.z + a1.z) + (a2.z + a3.z);
    A.w = (a0.w + a1.w) + (a2.w + a3.w);
    // reduce across the 4 edge slots (lanes l, l+16, l+32, l+48)
    A.x += __shfl_xor(A.x, 16, 64); A.y += __shfl_xor(A.y, 16, 64);
    A.z += __shfl_xor(A.z, 16, 64); A.w += __shfl_xor(A.w, 16, 64);
    A.x += __shfl_xor(A.x, 32, 64); A.y += __shfl_xor(A.y, 32, 64);
    A.z += __shfl_xor(A.z, 32, 64); A.w += __shfl_xor(A.w, 32, 64);

    if (q == 0) {
        float dn = dinv[n];
        float d2 = dn * dn;
        float4 self = ((const float4*)hw)[(size_t)n * 16 + l];   // exact fp32 self term
        float4 bb = ((const float4*)bias)[l];
        float4 o;
        o.x = A.x + d2 * self.x + bb.x;
        o.y = A.y + d2 * self.y + bb.y;
        o.z = A.z + d2 * self.z + bb.z;
        o.w = A.w + d2 * self.w + bb.w;
        ((float4*)hout)[(size_t)n * 16 + l] = o;
    }
}

__global__ __launch_bounds__(256) void spill_agg_kernel(
    const int4* __restrict__ spill, const int* __restrict__ spillCnt,
    const float* __restrict__ hw, const float* __restrict__ dinv, float* __restrict__ hout)
{
    int gid = blockIdx.x * blockDim.x + threadIdx.x;
    int e = gid >> 6, lane = gid & 63;
    int ns = min(*spillCnt, SPILL_CAP);
    if (e >= ns) return;
    int4 sp = spill[e];
    float nm = dinv[sp.x] * __int_as_float(sp.z) * dinv[sp.y];
    atomicAdd(&hout[(size_t)sp.y * HDIM + lane], nm * hw[(size_t)sp.x * HDIM + lane]);
}

// ================= shared: GEMM (float4 LDS; dual fp32+bf16 output) =================

template<int LAYER>
__global__ __launch_bounds__(256) void gemm_kernel(
    const float* __restrict__ x, const int* __restrict__ mapping,
    const float* __restrict__ emb, const float* __restrict__ hin,
    const float* __restrict__ W, float* __restrict__ hw,
    unsigned short* __restrict__ hw16, int N)
{
    __shared__ __align__(16) float ins[64][HDIM];   // 16 KB
    int t = threadIdx.x;
    int nodeBase = blockIdx.x * 64;

    for (int i = t; i < 64 * 16; i += 256) {
        int nr = i >> 4, q = i & 15;
        int n = nodeBase + nr;
        float4 v4 = {0.f, 0.f, 0.f, 0.f};
        if (n < N) {
            if (LAYER == 0) {
                if (q < 8) v4 = ((const float4*)(x   + (size_t)n * NFEAT))[q];
                else       v4 = ((const float4*)(emb + (size_t)mapping[n] * NEMB))[q - 8];
            } else {
                float4 h4 = ((const float4*)(hin + (size_t)n * HDIM))[q];
                v4.x = fmaxf(h4.x, 0.f); v4.y = fmaxf(h4.y, 0.f);
                v4.z = fmaxf(h4.z, 0.f); v4.w = fmaxf(h4.w, 0.f);
            }
        }
        ((float4*)ins[nr])[q] = v4;
    }

    int k = t & 63;
    float wcol[HDIM];
    #pragma unroll
    for (int kk = 0; kk < HDIM; ++kk) wcol[kk] = W[kk * HDIM + k];
    __syncthreads();

    int nl = t >> 6;
    for (int ns = 0; ns < 16; ++ns) {
        int nrow = ns * 4 + nl;
        int n = nodeBase + nrow;
        float acc = 0.f;
        #pragma unroll
        for (int q = 0; q < 16; ++q) {
            float4 iv = ((const float4*)ins[nrow])[q];
            acc += iv.x * wcol[4*q]     + iv.y * wcol[4*q + 1]
                 + iv.z * wcol[4*q + 2] + iv.w * wcol[4*q + 3];
        }
        if (n < N) {
            hw[(size_t)n * HDIM + k] = acc;
            if (hw16) hw16[(size_t)n * HDIM + k] = f_to_bf16(acc);
        }
    }
}

// ================= tier 2: ELL path =================

__global__ void init_ell_kernel(int* __restrict__ cnt, int* __restrict__ spillCnt, int N) {
    int i = blockIdx.x * blockDim.x + threadIdx.x;
    if (i < N) cnt[i] = 0;
    if (i == 0) *spillCnt = 0;
}

__global__ void ell_fill_kernel(const int* __restrict__ ei, const float* __restrict__ ew,
                                int* __restrict__ cnt, int2* __restrict__ ell,
                                int4* __restrict__ spill, int* __restrict__ spillCnt, int E) {
    int e = blockIdx.x * blockDim.x + threadIdx.x;
    if (e >= E) return;
    int src = ei[e];
    int dst = ei[E + e];
    float w = ew[e];
    int slot = atomicAdd(&cnt[dst], 1);
    if (slot < MAXD) {
        ell[(size_t)dst * MAXD + slot] = make_int2(src, __float_as_int(w));
    } else {
        int sp = atomicAdd(spillCnt, 1);
        if (sp < SPILL_CAP) spill[sp] = make_int4(src, dst, __float_as_int(w), 0);
    }
}

__global__ __launch_bounds__(256) void degsum_kernel(const int2* __restrict__ ell,
                                                     const int* __restrict__ cnt,
                                                     float* __restrict__ deg, int N) {
    int gid = blockIdx.x * blockDim.x + threadIdx.x;
    int n = gid >> 6, lane = gid & 63;
    if (n >= N) return;
    int c = min(cnt[n], MAXD);
    float s = (lane < c) ? __int_as_float(ell[(size_t)n * MAXD + lane].y) : 0.f;
    #pragma unroll
    for (int d = 32; d > 0; d >>= 1) s += __shfl_down(s, d, 64);
    if (lane == 0) deg[n] = 1.f + s;
}

__global__ __launch_bounds__(256) void agg_kernel(
    const int2* __restrict__ ell, const int* __restrict__ cnt,
    const float* __restrict__ hw, const float* __restrict__ dinv,
    const float* __restrict__ bias, float* __restrict__ hout, int N)
{
    int gid = blockIdx.x * blockDim.x + threadIdx.x;
    int n = gid >> 6, lane = gid & 63;
    if (n >= N) return;
    int c = min(cnt[n], MAXD);
    const int2* row = ell + (size_t)n * MAXD;
    float acc0 = 0.f, acc1 = 0.f;
    int j = 0;
    for (; j + 1 < c; j += 2) {
        int2 e0 = row[j], e1 = row[j + 1];
        acc0 += dinv[e0.x] * __int_as_float(e0.y) * hw[(size_t)e0.x * HDIM + lane];
        acc1 += dinv[e1.x] * __int_as_float(e1.y) * hw[(size_t)e1.x * HDIM + lane];
    }
    if (j < c) {
        int2 e0 = row[j];
        acc0 += dinv[e0.x] * __int_as_float(e0.y) * hw[(size_t)e0.x * HDIM + lane];
    }
    float dn = dinv[n];
    hout[(size_t)n * HDIM + lane] =
        dn * (acc0 + acc1) + dn * dn * hw[(size_t)n * HDIM + lane] + bias[lane];
}

// ================= tier 3: atomic scatter =================

__global__ void init_kernel(float* __restrict__ deg, int* __restrict__ cnt, int N) {
    int i = blockIdx.x * blockDim.x + threadIdx.x;
    if (i < N) { deg[i] = 1.0f; cnt[i] = 0; }
}

__global__ void hist_kernel(const int* __restrict__ ei, const float* __restrict__ ew,
                            float* __restrict__ deg, int* __restrict__ cnt, int E) {
    int e = blockIdx.x * blockDim.x + threadIdx.x;
    if (e < E) {
        int dst = ei[E + e];
        atomicAdd(&deg[dst], ew[e]);
        atomicAdd(&cnt[dst], 1);
    }
}

__global__ void self_init_kernel(const float* __restrict__ hw, const float* __restrict__ dinv,
                                 const float* __restrict__ b, float* __restrict__ hout, int NF) {
    int i = blockIdx.x * blockDim.x + threadIdx.x;
    if (i < NF) {
        int n = i >> 6, f = i & 63;
        float di = dinv[n];
        hout[i] = b[f] + di * di * hw[i];
    }
}

__global__ __launch_bounds__(256) void scatter_kernel(
    const int* __restrict__ ei, const float* __restrict__ ew,
    const float* __restrict__ dinv, const float* __restrict__ hw,
    float* __restrict__ hout, int E)
{
    int gid = blockIdx.x * blockDim.x + threadIdx.x;
    int e = gid >> 5, lane = gid & 31;
    if (e >= E) return;
    int src = ei[e];
    int dst = ei[E + e];
    float norm = dinv[src] * ew[e] * dinv[dst];
    float2 v = ((const float2*)hw)[(size_t)src * (HDIM / 2) + lane];
    float* o = &hout[(size_t)dst * HDIM + 2 * lane];
    atomicAdd(o,     norm * v.x);
    atomicAdd(o + 1, norm * v.y);
}

// ================= pooling: POOLSPLIT blocks per graph + atomic merge =================

__global__ void zero_out_kernel(float* __restrict__ out) {
    int i = blockIdx.x * blockDim.x + threadIdx.x;
    if (i < GBATCH * HDIM) out[i] = 0.f;
}

__global__ __launch_bounds__(256) void pool_kernel(
    const float* __restrict__ h, const int* __restrict__ batch,
    float* __restrict__ out, int N)
{
    int g = blockIdx.x / POOLSPLIT;
    int slice = blockIdx.x % POOLSPLIT;
    int t = threadIdx.x;
    int lane = t & 63, w = t >> 6;

    int lo = 0, hi = N;
    while (lo < hi) { int m = (lo + hi) >> 1; if (batch[m] < g) lo = m + 1; else hi = m; }
    int start = lo;
    hi = N;
    while (lo < hi) { int m = (lo + hi) >> 1; if (batch[m] < g + 1) lo = m + 1; else hi = m; }
    int end = lo;

    float acc = 0.f;
    for (int n = start + slice * 4 + w; n < end; n += POOLSPLIT * 4)
        acc += fmaxf(h[(size_t)n * HDIM + lane], 0.f);

    __shared__ float red[4][HDIM];
    red[w][lane] = acc;
    __syncthreads();
    if (w == 0) {
        float s = red[0][lane] + red[1][lane] + red[2][lane] + red[3][lane];
        if (s != 0.f || slice == 0) atomicAdd(&out[g * HDIM + lane], s);
    }
}

__global__ void div_kernel(float* __restrict__ out, const int* __restrict__ batch, int N) {
    int i = blockIdx.x * blockDim.x + threadIdx.x;
    if (i >= GBATCH * HDIM) return;
    int g = i >> 6;
    int lo = 0, hi = N;
    while (lo < hi) { int m = (lo + hi) >> 1; if (batch[m] < g) lo = m + 1; else hi = m; }
    int start = lo;
    hi = N;
    while (lo < hi) { int m = (lo + hi) >> 1; if (batch[m] < g + 1) lo = m + 1; else hi = m; }
    float c = (float)(lo - start);
    out[i] /= fmaxf(c, 1.f);
}

// ================= launch =================

extern "C" void kernel_launch(void* const* d_in, const int* in_sizes, int n_in,
                              void* d_out, int out_size, void* d_ws, size_t ws_size,
                              hipStream_t stream) {
    const float* x       = (const float*)d_in[0];
    const int*   mapping = (const int*)  d_in[1];
    const int*   ei      = (const int*)  d_in[2];
    const float* ew      = (const float*)d_in[3];
    const int*   batch   = (const int*)  d_in[4];
    const float* emb     = (const float*)d_in[5];
    const float* W0      = (const float*)d_in[6];
    const float* b0      = (const float*)d_in[7];
    const float* W1      = (const float*)d_in[8];
    const float* b1      = (const float*)d_in[9];
    float* out = (float*)d_out;

    const int N = in_sizes[1];
    const int E = in_sizes[2] / 2;

    const int gemmGrid = (N + 63) / 64;
    const int nodeGrid = (N * 64 + 255) / 256;
    const int spillGrid = (SPILL_CAP * 64 + 255) / 256;

    // tier-1: bucket | bufA | bufB | bufA16 | deg | off | ncnt | bucketCnt | spill | spillCnt
    size_t need_part = (size_t)NBUCK * BCAP * 8 + (size_t)N * HDIM * 4 * 2
                     + (size_t)N * HDIM * 2
                     + (size_t)N * 4 * 3 + (size_t)NBUCK * 4 + (size_t)SPILL_CAP * 16 + 16;
    size_t need_ell = (size_t)N * MAXD * 8 + (size_t)N * HDIM * 4 * 2 + (size_t)N * 4 * 2
                    + (size_t)SPILL_CAP * 16 + 16;

    if (ws_size >= need_part && N <= (NBUCK << BSHIFT) && N <= (1 << SRCBITS)) {
        char* p = (char*)d_ws;
        int2*  bucket    = (int2*)p;           p += (size_t)NBUCK * BCAP * 8;
        float* bufA      = (float*)p;          p += (size_t)N * HDIM * 4;
        float* bufB      = (float*)p;          p += (size_t)N * HDIM * 4;
        unsigned short* bufA16 = (unsigned short*)p;  p += (size_t)N * HDIM * 2;
        float* deg       = (float*)p;          p += (size_t)N * 4;
        int*   off       = (int*)p;            p += (size_t)N * 4;
        int*   ncnt      = (int*)p;            p += (size_t)N * 4;
        int*   bucketCnt = (int*)p;            p += (size_t)NBUCK * 4;
        int4*  spill     = (int4*)p;           p += (size_t)SPILL_CAP * 16;
        int*   spillCnt  = (int*)p;

        const int nChunks = (E + CHUNK - 1) / CHUNK;

        zero_part_kernel<<<(NBUCK + 255) / 256, 256, 0, stream>>>(bucketCnt, spillCnt);
        partition_kernel<<<nChunks, PBLOCK, 0, stream>>>(ei, ew, bucketCnt, bucket, spill, spillCnt, E);
        localsort_kernel<<<NBUCK, 256, 0, stream>>>(bucket, bucketCnt, off, ncnt, deg, N);
        spill_deg_kernel<<<(SPILL_CAP + 255) / 256, 256, 0, stream>>>(spill, spillCnt, deg);
        dinv_kernel<<<(N + 255) / 256, 256, 0, stream>>>(deg, N);
        norm_kernel<<<NBUCK, 256, 0, stream>>>(bucket, bucketCnt, deg);

        gemm_kernel<0><<<gemmGrid, 256, 0, stream>>>(x, mapping, emb, nullptr, W0, bufA, bufA16, N);
        agg2_kernel<<<nodeGrid, 256, 0, stream>>>(off, ncnt, bucket, bufA, bufA16, deg, b0, bufB, N);
        spill_agg_kernel<<<spillGrid, 256, 0, stream>>>(spill, spillCnt, bufA, deg, bufB);

        gemm_kernel<1><<<gemmGrid, 256, 0, stream>>>(nullptr, nullptr, nullptr, bufB, W1, bufA, bufA16, N);
        agg2_kernel<<<nodeGrid, 256, 0, stream>>>(off, ncnt, bucket, bufA, bufA16, deg, b1, bufB, N);
        spill_agg_kernel<<<spillGrid, 256, 0, stream>>>(spill, spillCnt, bufA, deg, bufB);

        zero_out_kernel<<<(GBATCH * HDIM + 255) / 256, 256, 0, stream>>>(out);
        pool_kernel<<<GBATCH * POOLSPLIT, 256, 0, stream>>>(bufB, batch, out, N);
        div_kernel<<<(GBATCH * HDIM + 255) / 256, 256, 0, stream>>>(out, batch, N);
    } else if (ws_size >= need_ell) {
        char* p = (char*)d_ws;
        int2*  ell  = (int2*)p;                p += (size_t)N * MAXD * 8;
        float* bufA = (float*)p;               p += (size_t)N * HDIM * 4;
        float* bufB = (float*)p;               p += (size_t)N * HDIM * 4;
        float* deg  = (float*)p;               p += (size_t)N * 4;
        int*   cnt  = (int*)p;                 p += (size_t)N * 4;
        int4*  spill = (int4*)p;               p += (size_t)SPILL_CAP * 16;
        int*   spillCnt = (int*)p;

        init_ell_kernel<<<(N + 255) / 256, 256, 0, stream>>>(cnt, spillCnt, N);
        ell_fill_kernel<<<(E + 255) / 256, 256, 0, stream>>>(ei, ew, cnt, ell, spill, spillCnt, E);
        degsum_kernel<<<nodeGrid, 256, 0, stream>>>(ell, cnt, deg, N);
        spill_deg_kernel<<<(SPILL_CAP + 255) / 256, 256, 0, stream>>>(spill, spillCnt, deg);
        dinv_kernel<<<(N + 255) / 256, 256, 0, stream>>>(deg, N);

        gemm_kernel<0><<<gemmGrid, 256, 0, stream>>>(x, mapping, emb, nullptr, W0, bufA, nullptr, N);
        agg_kernel<<<nodeGrid, 256, 0, stream>>>(ell, cnt, bufA, deg, b0, bufB, N);
        spill_agg_kernel<<<spillGrid, 256, 0, stream>>>(spill, spillCnt, bufA, deg, bufB);

        gemm_kernel<1><<<gemmGrid, 256, 0, stream>>>(nullptr, nullptr, nullptr, bufB, W1, bufA, nullptr, N);
        agg_kernel<<<nodeGrid, 256, 0, stream>>>(ell, cnt, bufA, deg, b1, bufB, N);
        spill_agg_kernel<<<spillGrid, 256, 0, stream>>>(spill, spillCnt, bufA, deg, bufB);

        zero_out_kernel<<<(GBATCH * HDIM + 255) / 256, 256, 0, stream>>>(out);
        pool_kernel<<<GBATCH * POOLSPLIT, 256, 0, stream>>>(bufB, batch, out, N);
        div_kernel<<<(GBATCH * HDIM + 255) / 256, 256, 0, stream>>>(out, batch, N);
    } else {
        char* p = (char*)d_ws;
        float* bufA = (float*)p;               p += (size_t)N * HDIM * 4;
        float* bufB = (float*)p;               p += (size_t)N * HDIM * 4;
        float* deg  = (float*)p;               p += (size_t)N * 4;
        int*   cnt  = (int*)p;

        const int NF = N * HDIM;
        const int scatGrid = (E * 32 + 255) / 256;
        init_kernel<<<(N + 255) / 256, 256, 0, stream>>>(deg, cnt, N);
        hist_kernel<<<(E + 255) / 256, 256, 0, stream>>>(ei, ew, deg, cnt, E);
        dinv_kernel<<<(N + 255) / 256, 256, 0, stream>>>(deg, N);

        gemm_kernel<0><<<gemmGrid, 256, 0, stream>>>(x, mapping, emb, nullptr, W0, bufA, nullptr, N);
        self_init_kernel<<<(NF + 255) / 256, 256, 0, stream>>>(bufA, deg, b0, bufB, NF);
        scatter_kernel<<<scatGrid, 256, 0, stream>>>(ei, ew, deg, bufA, bufB, E);

        gemm_kernel<1><<<gemmGrid, 256, 0, stream>>>(nullptr, nullptr, nullptr, bufB, W1, bufA, nullptr, N);
        self_init_kernel<<<(NF + 255) / 256, 256, 0, stream>>>(bufA, deg, b1, bufB, NF);
        scatter_kernel<<<scatGrid, 256, 0, stream>>>(ei, ew, deg, bufA, bufB, E);

        zero_out_kernel<<<(GBATCH * HDIM + 255) / 256, 256, 0, stream>>>(out);
        pool_kernel<<<GBATCH * POOLSPLIT, 256, 0, stream>>>(bufB, batch, out, N);
        div_kernel<<<(GBATCH * HDIM + 255) / 256, 256, 0, stream>>>(out, batch, N);
    }
}